// Round 3
// baseline (921.850 us; speedup 1.0000x reference)
//
#include <hip/hip_runtime.h>

#define BB 8
#define VV 1200
#define DD 64
#define KH 2     // hops
#define NH 4     // heads
#define CAP 64        // hop1 cap
#define NB2CAP 384    // hop2 cap
#define NROW (BB*VV)          // 9600
#define NKROW (KH*BB*VV)      // 19200

__device__ __forceinline__ float wredsum(float v) {
#pragma unroll
  for (int o = 32; o > 0; o >>= 1) v += __shfl_xor(v, o, 64);
  return v;
}

__device__ __forceinline__ float sigmoidf_(float x) { return 1.0f / (1.0f + expf(-x)); }

// row -> base in the nb_cols int array
__device__ __forceinline__ size_t nb_base(int row) {
  return (row < NROW) ? (size_t)row * CAP
                      : (size_t)NROW * CAP + (size_t)(row - NROW) * NB2CAP;
}

// ---------------- build CSR of binary neighborhoods (dense 92MB read once) ----------------
__global__ void __launch_bounds__(256) k_nbcsr(
    const float* __restrict__ nb,
    int* __restrict__ nb_cols, int* __restrict__ nb_cnt) {
  int wid = threadIdx.x >> 6, lane = threadIdx.x & 63;
  int row = blockIdx.x * 4 + wid;
  if (row >= NKROW) return;
  const float* nbrow = nb + (size_t)row * VV;
  size_t base = nb_base(row);
  int cap = (row < NROW) ? CAP : NB2CAP;
  unsigned long long ltmask = (lane == 0) ? 0ull : ((1ull << lane) - 1ull);
  int cnt = 0;
  for (int b0 = 0; b0 < VV; b0 += 64) {
    int v = b0 + lane;
    float val = (v < VV) ? nbrow[v] : 0.0f;
    unsigned long long mask = __ballot(val != 0.0f);
    int off = cnt + __popcll(mask & ltmask);
    if (val != 0.0f && off < cap) nb_cols[base + off] = v;
    cnt += __popcll(mask);
  }
  if (lane == 0) nb_cnt[row] = (cnt > cap) ? cap : cnt;
}

// ---------------- encoder: GEMM-tiled, 64 rows/block ----------------
__global__ void __launch_bounds__(256) k_encoder(
    const float* __restrict__ emb, const float* __restrict__ feat,
    const float* __restrict__ w0, const float* __restrict__ b0,
    const float* __restrict__ w1, const float* __restrict__ b1,
    float* __restrict__ enc0) {
  __shared__ float xT[64][25];
  __shared__ float hT[64][65];
  int tid = threadIdx.x, lane = tid & 63;
  int tile0 = blockIdx.x * 64;
  for (int rep = 0; rep < 4; ++rep) {
    int idx = rep * 256 + tid; int i = idx >> 4, d = idx & 15;
    xT[i][d] = emb[(size_t)(tile0 + i) * 16 + d];
  }
  for (int rep = 0; rep < 2; ++rep) {
    int idx = rep * 256 + tid; int i = idx >> 3, d = idx & 7;
    xT[i][16 + d] = feat[(size_t)(tile0 + i) * 8 + d];
  }
  __syncthreads();
  int jb = __builtin_amdgcn_readfirstlane((tid >> 6) * 16);
  float acc[16];
#pragma unroll
  for (int jj = 0; jj < 16; ++jj) acc[jj] = b0[jb + jj];
  for (int kk = 0; kk < 24; ++kk) {
    float x = xT[lane][kk];
#pragma unroll
    for (int jj = 0; jj < 16; ++jj) acc[jj] = fmaf(x, w0[kk * DD + jb + jj], acc[jj]);
  }
#pragma unroll
  for (int jj = 0; jj < 16; ++jj) hT[lane][jb + jj] = tanhf(acc[jj]);
  __syncthreads();
  float a2[16];
#pragma unroll
  for (int jj = 0; jj < 16; ++jj) a2[jj] = b1[jb + jj];
  for (int kk = 0; kk < DD; ++kk) {
    float x = hT[lane][kk];
#pragma unroll
    for (int jj = 0; jj < 16; ++jj) a2[jj] = fmaf(x, w1[kk * DD + jb + jj], a2[jj]);
  }
  __syncthreads();
#pragma unroll
  for (int jj = 0; jj < 16; ++jj) hT[lane][jb + jj] = tanhf(a2[jj]);
  __syncthreads();
  for (int rep = 0; rep < 16; ++rep) {
    int idx = rep * 256 + tid; int i = idx >> 6, d = idx & 63;
    enc0[(size_t)(tile0 + i) * DD + d] = hT[i][d];
  }
}

// ------- layer A: gather msg + agg GEMM + attention scores (64 rows/block) -------
__global__ void __launch_bounds__(256) k_msg_agg_att(
    const int* __restrict__ nb_cols, const int* __restrict__ nb_cnt,
    const float* __restrict__ encIn,
    const float* __restrict__ agg_w, const float* __restrict__ agg_b,
    const float* __restrict__ att_w, const float* __restrict__ att_b,
    const float* __restrict__ att_v,
    float* __restrict__ agg, float* __restrict__ scores) {
  __shared__ float msgT[64][65];
  __shared__ float aggT[64][65];
  __shared__ float scp[4][NH][64];
  int tid = threadIdx.x;
  int w = tid >> 6, lane = tid & 63;
  int tile0 = blockIdx.x * 64;            // [0, NKROW)
  int k = tile0 / NROW;                   // uniform per block (NROW % 64 == 0)
  int bv0 = tile0 - k * NROW;
  // ---- phase 1: gather 16 rows per wave ----
  for (int r = 0; r < 16; ++r) {
    int rowU = __builtin_amdgcn_readfirstlane(tile0 + w * 16 + r);
    int i = rowU - tile0;
    int bvU = rowU - k * NROW;
    int bU = bvU / VV;
    const float* encB = encIn + (size_t)bU * VV * DD;
    const int* cols = nb_cols + nb_base(rowU);
    int n = nb_cnt[rowU];
    float acc = 0.0f;
    int j = 0;
    for (; j + 8 <= n; j += 8) {
      int c0 = cols[j], c1 = cols[j+1], c2 = cols[j+2], c3 = cols[j+3];
      int c4 = cols[j+4], c5 = cols[j+5], c6 = cols[j+6], c7 = cols[j+7];
      float l0 = encB[(size_t)c0 * DD + lane];
      float l1 = encB[(size_t)c1 * DD + lane];
      float l2 = encB[(size_t)c2 * DD + lane];
      float l3 = encB[(size_t)c3 * DD + lane];
      float l4 = encB[(size_t)c4 * DD + lane];
      float l5 = encB[(size_t)c5 * DD + lane];
      float l6 = encB[(size_t)c6 * DD + lane];
      float l7 = encB[(size_t)c7 * DD + lane];
      acc += ((l0 + l1) + (l2 + l3)) + ((l4 + l5) + (l6 + l7));
    }
    for (; j < n; ++j) acc += encB[(size_t)cols[j] * DD + lane];
    msgT[i][lane] = acc / fmaxf((float)n, 1.0f);
  }
  __syncthreads();
  // ---- phase 2: agg = tanh(msg @ agg_w[k] + agg_b[k]) ----
  int jb = __builtin_amdgcn_readfirstlane(w * 16);
  const float* W = agg_w + (size_t)k * DD * DD;
  float acc[16];
#pragma unroll
  for (int jj = 0; jj < 16; ++jj) acc[jj] = agg_b[k * DD + jb + jj];
  for (int kk = 0; kk < DD; ++kk) {
    float a = msgT[lane][kk];
#pragma unroll
    for (int jj = 0; jj < 16; ++jj) acc[jj] = fmaf(a, W[kk * DD + jb + jj], acc[jj]);
  }
#pragma unroll
  for (int jj = 0; jj < 16; ++jj) aggT[lane][jb + jj] = tanhf(acc[jj]);
  __syncthreads();
  // ---- phase 3: attention scores ----
  for (int h = 0; h < NH; ++h) {
    const float* Wh = att_w + (size_t)h * DD * DD;
    float a2[16];
#pragma unroll
    for (int jj = 0; jj < 16; ++jj) a2[jj] = att_b[h * DD + jb + jj];
    for (int kk = 0; kk < DD; ++kk) {
      float a = aggT[lane][kk];
#pragma unroll
      for (int jj = 0; jj < 16; ++jj) a2[jj] = fmaf(a, Wh[kk * DD + jb + jj], a2[jj]);
    }
    float p = 0.0f;
#pragma unroll
    for (int jj = 0; jj < 16; ++jj) p += tanhf(a2[jj]) * att_v[h * DD + jb + jj];
    scp[w][h][lane] = p;
  }
  __syncthreads();
  {
    int h = tid >> 6, i = tid & 63;
    float s = scp[0][h][i] + scp[1][h][i] + scp[2][h][i] + scp[3][h][i];
    scores[(size_t)(h * KH + k) * NROW + bv0 + i] = s;
  }
  for (int rep = 0; rep < 16; ++rep) {
    int idx = rep * 256 + tid; int i = idx >> 6, d = idx & 63;
    agg[(size_t)(tile0 + i) * DD + d] = aggT[i][d];
  }
}

// ------- layer B: attention mix + GRU (+ fused decode), 64 bv-rows/block -------
__global__ void __launch_bounds__(256) k_att_gru(
    const float* __restrict__ encIn, const float* __restrict__ agg,
    const float* __restrict__ scores,
    const float* __restrict__ wu, const float* __restrict__ bu,
    const float* __restrict__ wr, const float* __restrict__ br,
    const float* __restrict__ wc, const float* __restrict__ bc,
    float* __restrict__ encOut,
    int do_decode,
    const float* __restrict__ dw0, const float* __restrict__ db0,
    const float* __restrict__ dw1, const float* __restrict__ db1,
    const float* __restrict__ uw0, const float* __restrict__ ub0,
    const float* __restrict__ uw1, const float* __restrict__ ub1,
    float* __restrict__ pred, float* __restrict__ dualp) {
  __shared__ float xsT[64][129];   // [row][0..63]=nxt, [64..127]=enc then r*enc
  __shared__ float rT[64][65];     // r, then reused as out tile
  __shared__ float w01[2][64];
  __shared__ float scred[4][2][64];
  int tid = threadIdx.x, w = tid >> 6, lane = tid & 63;
  int tile0 = blockIdx.x * 64;
  for (int rep = 0; rep < 16; ++rep) {
    int idx = rep * 256 + tid; int i = idx >> 6, d = idx & 63;
    xsT[i][64 + d] = encIn[(size_t)(tile0 + i) * DD + d];
  }
  if (tid < 64) {
    int i = tid;
    float W0 = 0.0f, W1 = 0.0f;
#pragma unroll
    for (int h = 0; h < NH; ++h) {
      float s0 = scores[(size_t)(h * KH + 0) * NROW + tile0 + i];
      float s1 = scores[(size_t)(h * KH + 1) * NROW + tile0 + i];
      float m = fmaxf(s0, s1);
      float e0 = expf(s0 - m), e1 = expf(s1 - m);
      float inv = 1.0f / (e0 + e1);
      W0 += e0 * inv; W1 += e1 * inv;
    }
    w01[0][i] = W0 * 0.25f; w01[1][i] = W1 * 0.25f;
  }
  __syncthreads();
  for (int rep = 0; rep < 16; ++rep) {
    int idx = rep * 256 + tid; int i = idx >> 6, d = idx & 63;
    float a0 = agg[(size_t)(tile0 + i) * DD + d];
    float a1 = agg[(size_t)(NROW + tile0 + i) * DD + d];
    xsT[i][d] = w01[0][i] * a0 + w01[1][i] * a1;
  }
  __syncthreads();
  int jb = __builtin_amdgcn_readfirstlane(w * 16);
  float au[16], ar[16];
#pragma unroll
  for (int jj = 0; jj < 16; ++jj) { au[jj] = bu[jb + jj]; ar[jj] = br[jb + jj]; }
  for (int kk = 0; kk < 2 * DD; ++kk) {
    float x = xsT[lane][kk];
#pragma unroll
    for (int jj = 0; jj < 16; ++jj) {
      au[jj] = fmaf(x, wu[kk * DD + jb + jj], au[jj]);
      ar[jj] = fmaf(x, wr[kk * DD + jb + jj], ar[jj]);
    }
  }
  float uu[16], encv[16];
#pragma unroll
  for (int jj = 0; jj < 16; ++jj) {
    uu[jj] = sigmoidf_(au[jj]);
    rT[lane][jb + jj] = sigmoidf_(ar[jj]);
    encv[jj] = xsT[lane][64 + jb + jj];
  }
  __syncthreads();
  for (int rep = 0; rep < 16; ++rep) {
    int idx = rep * 256 + tid; int i = idx >> 6, d = idx & 63;
    xsT[i][64 + d] *= rT[i][d];
  }
  __syncthreads();
  float ac[16];
#pragma unroll
  for (int jj = 0; jj < 16; ++jj) ac[jj] = bc[jb + jj];
  for (int kk = 0; kk < 2 * DD; ++kk) {
    float x = xsT[lane][kk];
#pragma unroll
    for (int jj = 0; jj < 16; ++jj) ac[jj] = fmaf(x, wc[kk * DD + jb + jj], ac[jj]);
  }
  __syncthreads();   // rT reads (multiply phase) done; safe to overwrite
#pragma unroll
  for (int jj = 0; jj < 16; ++jj) {
    float cc = tanhf(ac[jj]);
    rT[lane][jb + jj] = uu[jj] * encv[jj] + (1.0f - uu[jj]) * cc;
  }
  __syncthreads();
  for (int rep = 0; rep < 16; ++rep) {
    int idx = rep * 256 + tid; int i = idx >> 6, d = idx & 63;
    encOut[(size_t)(tile0 + i) * DD + d] = rT[i][d];
  }
  if (do_decode) {
    float hd[16], hq[16];
#pragma unroll
    for (int jj = 0; jj < 16; ++jj) { hd[jj] = db0[jb + jj]; hq[jj] = ub0[jb + jj]; }
    for (int kk = 0; kk < DD; ++kk) {
      float x = rT[lane][kk];
#pragma unroll
      for (int jj = 0; jj < 16; ++jj) {
        hd[jj] = fmaf(x, dw0[kk * DD + jb + jj], hd[jj]);
        hq[jj] = fmaf(x, uw0[kk * DD + jb + jj], hq[jj]);
      }
    }
    float p = 0.0f, q = 0.0f;
#pragma unroll
    for (int jj = 0; jj < 16; ++jj) { p += hd[jj] * dw1[jb + jj]; q += hq[jj] * uw1[jb + jj]; }
    scred[w][0][lane] = p; scred[w][1][lane] = q;
    __syncthreads();
    if (tid < 64) {
      pred[tile0 + tid] = scred[0][0][tid] + scred[1][0][tid] + scred[2][0][tid] + scred[3][0][tid] + db1[0];
    } else if (tid < 128) {
      int i = tid - 64;
      dualp[tile0 + i] = scred[0][1][i] + scred[1][1][i] + scred[2][1][i] + scred[3][1][i] + ub1[0];
    }
  }
}

// ------- fused: sparsemax (fixed-point tau) + CSC scatter + dual edge cost -------
__global__ void __launch_bounds__(256) k_primal_dual(
    const int* __restrict__ nb_cols, const int* __restrict__ nb_cnt,
    const float* __restrict__ pred, const float* __restrict__ dualp,
    const float* __restrict__ dem,
    float* __restrict__ rowsum,
    int* __restrict__ col_cnt, int* __restrict__ col_rows, float* __restrict__ col_vals,
    float* __restrict__ out) {
  __shared__ float bacc[BB];
  if (threadIdx.x < BB) bacc[threadIdx.x] = 0.0f;
  __syncthreads();
  int w = threadIdx.x >> 6, lane = threadIdx.x & 63;
  int row = blockIdx.x * 4 + w;
  int b = row / VV;
  int n = nb_cnt[row];
  int c = (lane < n) ? nb_cols[(size_t)row * CAP + lane] : 0;
  const float* predB = pred + (size_t)b * VV;
  const float* dualB = dualp + (size_t)b * VV;
  float z = (lane < n) ? predB[c] : -1e30f;
  float tau = 0.0f;
  if (n > 0) {
    bool in = (lane < n);
    for (int it = 0; it < 64; ++it) {
      float s = wredsum(in ? z : 0.0f);
      int cnt = (int)__popcll(__ballot(in));
      tau = (s - 1.0f) / (float)cnt;
      bool nin = (z > tau);
      if (__ballot(nin) == __ballot(in)) break;
      in = nin;
    }
  }
  float pv = (lane < n) ? fmaxf(z - tau, 0.0f) : 0.0f;
  float s2 = wredsum(pv * pv);
  if (lane == 0) rowsum[row] = s2;
  // CSC scatter (only nonzero props carry flow)
  if (pv > 0.0f) {
    int g = b * VV + c;
    int j = atomicAdd(&col_cnt[g], 1);
    if (j < CAP) {
      col_rows[(size_t)g * CAP + j] = row - b * VV;
      col_vals[(size_t)g * CAP + j] = pv;
    }
  }
  // dual edge cost
  float du = dualp[row];
  float es = 0.0f;
  if (lane < n) {
    float dd = du - dualB[c];
    float f = 0.0f, acm = 0.0f;
#pragma unroll
    for (int t = 0; t < 8; ++t) {
      float look = f - 0.9f * acm;
      float grad = 2.0f * look - dd;
      acm = 0.9f * acm + 0.1f * grad;
      f = fmaxf(f - acm, 0.0f);
    }
    es = f * f - dd * f;
  }
  float contrib = -es;
  if (lane == 0) contrib += du * dem[row];
  float ws_ = wredsum(contrib);
  if (lane == 0) atomicAdd(&bacc[b], ws_);
  __syncthreads();
  if (threadIdx.x < BB) {
    float t = bacc[threadIdx.x];
    if (t != 0.0f) atomicAdd(&out[threadIdx.x], t);
  }
}

// ------- fused flow iterations (per-graph block) + flow cost -------
__global__ void __launch_bounds__(1024) k_flow(
    const int* __restrict__ col_cnt, const int* __restrict__ col_rows,
    const float* __restrict__ col_vals, const float* __restrict__ dem,
    const float* __restrict__ rowsum, float* __restrict__ out) {
  __shared__ float aS[VV];
  __shared__ float red[16];
  int b = blockIdx.x;
  int tid = threadIdx.x;
  const float* demB = dem + (size_t)b * VV;
  for (int v = tid; v < VV; v += 1024) aS[v] = fmaxf(-demB[v], 0.0f);
  __syncthreads();
  for (int t = 0; t < 7; ++t) {
    float nv0 = 0.0f, nv1 = 0.0f;
    {
      int v = tid;
      if (v < VV) {
        int g = b * VV + v;
        int n = col_cnt[g]; if (n > CAP) n = CAP;
        const int* cr = col_rows + (size_t)g * CAP;
        const float* cv = col_vals + (size_t)g * CAP;
        float acc = 0.0f;
        for (int j = 0; j < n; ++j) acc += cv[j] * aS[cr[j]];
        nv0 = fmaxf(acc - demB[v], 0.0f);
      }
      v = tid + 1024;
      if (v < VV) {
        int g = b * VV + v;
        int n = col_cnt[g]; if (n > CAP) n = CAP;
        const int* cr = col_rows + (size_t)g * CAP;
        const float* cv = col_vals + (size_t)g * CAP;
        float acc = 0.0f;
        for (int j = 0; j < n; ++j) acc += cv[j] * aS[cr[j]];
        nv1 = fmaxf(acc - demB[v], 0.0f);
      }
    }
    __syncthreads();
    if (tid < VV) aS[tid] = nv0;
    if (tid + 1024 < VV) aS[tid + 1024] = nv1;
    __syncthreads();
  }
  float fc = 0.0f;
  for (int v = tid; v < VV; v += 1024) { float a = aS[v]; fc += a * a * rowsum[b * VV + v]; }
  fc = wredsum(fc);
  int wid = tid >> 6, lane = tid & 63;
  if (lane == 0) red[wid] = fc;
  __syncthreads();
  if (tid == 0) {
    float s = 0.0f;
#pragma unroll
    for (int i = 0; i < 16; ++i) s += red[i];
    atomicAdd(&out[b], s);
  }
}

extern "C" void kernel_launch(void* const* d_in, const int* in_sizes, int n_in,
                              void* d_out, int out_size, void* d_ws, size_t ws_size,
                              hipStream_t stream) {
  const float* feat   = (const float*)d_in[0];
  const float* emb    = (const float*)d_in[1];
  const float* dem    = (const float*)d_in[2];
  const float* nb     = (const float*)d_in[4];   // [K,B,V,V]
  const float* enc_w0 = (const float*)d_in[5];
  const float* enc_b0 = (const float*)d_in[6];
  const float* enc_w1 = (const float*)d_in[7];
  const float* enc_b1 = (const float*)d_in[8];
  const float* agg_w  = (const float*)d_in[9];
  const float* agg_b  = (const float*)d_in[10];
  const float* att_w  = (const float*)d_in[11];
  const float* att_b  = (const float*)d_in[12];
  const float* att_v  = (const float*)d_in[13];
  const float* gru_wu = (const float*)d_in[14];
  const float* gru_bu = (const float*)d_in[15];
  const float* gru_wr = (const float*)d_in[16];
  const float* gru_br = (const float*)d_in[17];
  const float* gru_wc = (const float*)d_in[18];
  const float* gru_bc = (const float*)d_in[19];
  const float* dec_w0 = (const float*)d_in[20];
  const float* dec_b0 = (const float*)d_in[21];
  const float* dec_w1 = (const float*)d_in[22];
  const float* dec_b1 = (const float*)d_in[23];
  const float* dual_w0= (const float*)d_in[24];
  const float* dual_b0= (const float*)d_in[25];
  const float* dual_w1= (const float*)d_in[26];
  const float* dual_b1= (const float*)d_in[27];
  float* out = (float*)d_out;

  float* ws = (float*)d_ws;
  float* enc0     = ws;                              // 614400
  float* enc1     = enc0 + (size_t)NROW * DD;        // 614400
  float* agg      = enc1 + (size_t)NROW * DD;        // 1228800
  float* scores   = agg + (size_t)NKROW * DD;        // 76800
  float* pred     = scores + (size_t)NH * KH * NROW;
  float* dualp    = pred + NROW;
  float* rowsum   = dualp + NROW;
  float* col_vals = rowsum + NROW;                   // 614400
  int* col_cnt  = (int*)(col_vals + (size_t)NROW * CAP);
  int* nb_cnt   = col_cnt + NROW;                    // 19200
  int* col_rows = nb_cnt + NKROW;                    // 614400
  int* nb_cols  = col_rows + (size_t)NROW * CAP;     // 9600*64 + 9600*384 ints

  (void)in_sizes; (void)n_in; (void)ws_size;

  hipMemsetAsync(out, 0, (size_t)out_size * sizeof(float), stream);
  hipMemsetAsync(col_cnt, 0, (size_t)NROW * sizeof(int), stream);

  k_nbcsr<<<NKROW / 4, 256, 0, stream>>>(nb, nb_cols, nb_cnt);
  k_encoder<<<NROW / 64, 256, 0, stream>>>(emb, feat, enc_w0, enc_b0, enc_w1, enc_b1, enc0);

  const float* encIn = enc0;
  float* encOut = enc1;
  for (int l = 0; l < 2; ++l) {
    k_msg_agg_att<<<NKROW / 64, 256, 0, stream>>>(nb_cols, nb_cnt, encIn, agg_w, agg_b,
                                                  att_w, att_b, att_v, agg, scores);
    k_att_gru<<<NROW / 64, 256, 0, stream>>>(encIn, agg, scores, gru_wu, gru_bu, gru_wr, gru_br,
                                             gru_wc, gru_bc, encOut,
                                             (l == 1) ? 1 : 0,
                                             dec_w0, dec_b0, dec_w1, dec_b1,
                                             dual_w0, dual_b0, dual_w1, dual_b1, pred, dualp);
    const float* t = encIn; encIn = encOut; encOut = (float*)t;
  }

  k_primal_dual<<<NROW / 4, 256, 0, stream>>>(nb_cols, nb_cnt, pred, dualp, dem,
                                              rowsum, col_cnt, col_rows, col_vals, out);
  k_flow<<<BB, 1024, 0, stream>>>(col_cnt, col_rows, col_vals, dem, rowsum, out);
}

// Round 4
// 748.489 us; speedup vs baseline: 1.2316x; 1.2316x over previous
//
#include <hip/hip_runtime.h>

#define BB 8
#define VV 1200
#define DD 64
#define KH 2     // hops
#define NH 4     // heads
#define CAP 64        // hop1 cap
#define NB2CAP 384    // hop2 cap
#define NROW (BB*VV)          // 9600
#define NKROW (KH*BB*VV)      // 19200

__device__ __forceinline__ float wredsum(float v) {
#pragma unroll
  for (int o = 32; o > 0; o >>= 1) v += __shfl_xor(v, o, 64);
  return v;
}

__device__ __forceinline__ float sigmoidf_(float x) { return 1.0f / (1.0f + expf(-x)); }

__device__ __forceinline__ size_t nb_base(int row) {
  return (row < NROW) ? (size_t)row * CAP
                      : (size_t)NROW * CAP + (size_t)(row - NROW) * NB2CAP;
}

// ---------------- build CSR of binary neighborhoods (dense 92MB read once) ----------------
__global__ void __launch_bounds__(256) k_nbcsr(
    const float* __restrict__ nb,
    int* __restrict__ nb_cols, int* __restrict__ nb_cnt) {
  int wid = threadIdx.x >> 6, lane = threadIdx.x & 63;
  int row = blockIdx.x * 4 + wid;
  if (row >= NKROW) return;
  const float* nbrow = nb + (size_t)row * VV;
  size_t base = nb_base(row);
  int cap = (row < NROW) ? CAP : NB2CAP;
  unsigned long long ltmask = (lane == 0) ? 0ull : ((1ull << lane) - 1ull);
  int cnt = 0;
  for (int b0 = 0; b0 < VV; b0 += 64) {
    int v = b0 + lane;
    float val = (v < VV) ? nbrow[v] : 0.0f;
    unsigned long long mask = __ballot(val != 0.0f);
    int off = cnt + __popcll(mask & ltmask);
    if (val != 0.0f && off < cap) nb_cols[base + off] = v;
    cnt += __popcll(mask);
  }
  if (lane == 0) nb_cnt[row] = (cnt > cap) ? cap : cnt;
}

// ---------------- encoder: GEMM-tiled, 64 rows/block ----------------
__global__ void __launch_bounds__(256) k_encoder(
    const float* __restrict__ emb, const float* __restrict__ feat,
    const float* __restrict__ w0, const float* __restrict__ b0,
    const float* __restrict__ w1, const float* __restrict__ b1,
    float* __restrict__ enc0) {
  __shared__ float xT[64][25];
  __shared__ float hT[64][65];
  int tid = threadIdx.x, lane = tid & 63;
  int tile0 = blockIdx.x * 64;
  for (int rep = 0; rep < 4; ++rep) {
    int idx = rep * 256 + tid; int i = idx >> 4, d = idx & 15;
    xT[i][d] = emb[(size_t)(tile0 + i) * 16 + d];
  }
  for (int rep = 0; rep < 2; ++rep) {
    int idx = rep * 256 + tid; int i = idx >> 3, d = idx & 7;
    xT[i][16 + d] = feat[(size_t)(tile0 + i) * 8 + d];
  }
  __syncthreads();
  int jb = __builtin_amdgcn_readfirstlane((tid >> 6) * 16);
  float acc[16];
#pragma unroll
  for (int jj = 0; jj < 16; ++jj) acc[jj] = b0[jb + jj];
  for (int kk = 0; kk < 24; ++kk) {
    float x = xT[lane][kk];
#pragma unroll
    for (int jj = 0; jj < 16; ++jj) acc[jj] = fmaf(x, w0[kk * DD + jb + jj], acc[jj]);
  }
#pragma unroll
  for (int jj = 0; jj < 16; ++jj) hT[lane][jb + jj] = tanhf(acc[jj]);
  __syncthreads();
  float a2[16];
#pragma unroll
  for (int jj = 0; jj < 16; ++jj) a2[jj] = b1[jb + jj];
  for (int kk = 0; kk < DD; ++kk) {
    float x = hT[lane][kk];
#pragma unroll
    for (int jj = 0; jj < 16; ++jj) a2[jj] = fmaf(x, w1[kk * DD + jb + jj], a2[jj]);
  }
#pragma unroll
  for (int jj = 0; jj < 16; ++jj) {
    enc0[(size_t)(tile0 + lane) * DD + jb + jj] = tanhf(a2[jj]);
  }
}

// ---------------- gather: wave per row, float4 lanes, high occupancy ----------------
__global__ void __launch_bounds__(256) k_gather(
    const int* __restrict__ nb_cols, const int* __restrict__ nb_cnt,
    const float* __restrict__ encIn, float* __restrict__ msg) {
  int w = threadIdx.x >> 6, lane = threadIdx.x & 63;
  int row = blockIdx.x * 4 + w;           // [0, NKROW)
  int k = (row >= NROW) ? 1 : 0;
  int bv = row - k * NROW;
  int b = bv / VV;
  const float4* enc4 = (const float4*)(encIn + (size_t)b * VV * DD);
  const int* cols = nb_cols + nb_base(row);
  int n = nb_cnt[row];
  int sub = lane >> 4, q = lane & 15;
  float ax = 0.0f, ay = 0.0f, az = 0.0f, aw = 0.0f;
  int j = 0;
  for (; j + 8 <= n; j += 8) {
    int c0 = cols[j + sub];
    int c1 = cols[j + 4 + sub];
    float4 v0 = enc4[(size_t)c0 * 16 + q];
    float4 v1 = enc4[(size_t)c1 * 16 + q];
    ax += v0.x + v1.x; ay += v0.y + v1.y; az += v0.z + v1.z; aw += v0.w + v1.w;
  }
  for (; j < n; j += 4) {
    int idx = j + sub;
    if (idx < n) {
      float4 v = enc4[(size_t)cols[idx] * 16 + q];
      ax += v.x; ay += v.y; az += v.z; aw += v.w;
    }
  }
#pragma unroll
  for (int o = 16; o < 64; o <<= 1) {
    ax += __shfl_xor(ax, o, 64);
    ay += __shfl_xor(ay, o, 64);
    az += __shfl_xor(az, o, 64);
    aw += __shfl_xor(aw, o, 64);
  }
  if (lane < 16) {
    float inv = 1.0f / fmaxf((float)n, 1.0f);
    float4 r; r.x = ax * inv; r.y = ay * inv; r.z = az * inv; r.w = aw * inv;
    ((float4*)(msg + (size_t)row * DD))[q] = r;
  }
}

// ---------------- layer: agg GEMM + attention + GRU (+ fused decode) ----------------
__global__ void __launch_bounds__(256) k_layer(
    const float* __restrict__ msg, const float* __restrict__ encIn,
    const float* __restrict__ agg_w, const float* __restrict__ agg_b,
    const float* __restrict__ att_w, const float* __restrict__ att_b,
    const float* __restrict__ att_v,
    const float* __restrict__ wu, const float* __restrict__ bu,
    const float* __restrict__ wr, const float* __restrict__ br,
    const float* __restrict__ wc, const float* __restrict__ bc,
    float* __restrict__ encOut,
    int do_decode,
    const float* __restrict__ dw0, const float* __restrict__ db0,
    const float* __restrict__ dw1, const float* __restrict__ db1,
    const float* __restrict__ uw0, const float* __restrict__ ub0,
    const float* __restrict__ uw1, const float* __restrict__ ub1,
    float* __restrict__ pred, float* __restrict__ dualp) {
  __shared__ float E[64][65];
  __shared__ float M0[64][65];
  __shared__ float M1[64][65];
  __shared__ float G0[64][65];
  __shared__ float G1[64][65];
  __shared__ float scp[4][NH][2][64];
  __shared__ float wmix[2][64];
  __shared__ float scred[4][2][64];
  int tid = threadIdx.x, w = tid >> 6, lane = tid & 63;
  int tile0 = blockIdx.x * 64;
  for (int rep = 0; rep < 16; ++rep) {
    int idx = rep * 256 + tid; int i = idx >> 6, d = idx & 63;
    E[i][d]  = encIn[(size_t)(tile0 + i) * DD + d];
    M0[i][d] = msg[(size_t)(tile0 + i) * DD + d];
    M1[i][d] = msg[(size_t)(NROW + tile0 + i) * DD + d];
  }
  __syncthreads();
  int jb = __builtin_amdgcn_readfirstlane(w * 16);
  // agg_k = tanh(msg_k @ agg_w[k] + agg_b[k])
  {
    float a0[16], a1[16];
#pragma unroll
    for (int jj = 0; jj < 16; ++jj) { a0[jj] = agg_b[jb + jj]; a1[jj] = agg_b[DD + jb + jj]; }
    for (int kk = 0; kk < DD; ++kk) {
      float x0 = M0[lane][kk], x1 = M1[lane][kk];
#pragma unroll
      for (int jj = 0; jj < 16; ++jj) {
        a0[jj] = fmaf(x0, agg_w[kk * DD + jb + jj], a0[jj]);
        a1[jj] = fmaf(x1, agg_w[(size_t)DD * DD + kk * DD + jb + jj], a1[jj]);
      }
    }
#pragma unroll
    for (int jj = 0; jj < 16; ++jj) {
      G0[lane][jb + jj] = tanhf(a0[jj]);
      G1[lane][jb + jj] = tanhf(a1[jj]);
    }
  }
  __syncthreads();
  // attention scores per head/hop
  for (int h = 0; h < NH; ++h) {
    const float* Wh = att_w + (size_t)h * DD * DD;
    float a0[16], a1[16];
#pragma unroll
    for (int jj = 0; jj < 16; ++jj) { a0[jj] = att_b[h * DD + jb + jj]; a1[jj] = a0[jj]; }
    for (int kk = 0; kk < DD; ++kk) {
      float x0 = G0[lane][kk], x1 = G1[lane][kk];
#pragma unroll
      for (int jj = 0; jj < 16; ++jj) {
        float ww = Wh[kk * DD + jb + jj];
        a0[jj] = fmaf(x0, ww, a0[jj]);
        a1[jj] = fmaf(x1, ww, a1[jj]);
      }
    }
    float p0 = 0.0f, p1 = 0.0f;
#pragma unroll
    for (int jj = 0; jj < 16; ++jj) {
      float vv = att_v[h * DD + jb + jj];
      p0 += tanhf(a0[jj]) * vv;
      p1 += tanhf(a1[jj]) * vv;
    }
    scp[w][h][0][lane] = p0;
    scp[w][h][1][lane] = p1;
  }
  __syncthreads();
  // softmax over hops -> mix weights
  if (tid < 64) {
    float W0 = 0.0f, W1 = 0.0f;
#pragma unroll
    for (int h = 0; h < NH; ++h) {
      float s0 = scp[0][h][0][tid] + scp[1][h][0][tid] + scp[2][h][0][tid] + scp[3][h][0][tid];
      float s1 = scp[0][h][1][tid] + scp[1][h][1][tid] + scp[2][h][1][tid] + scp[3][h][1][tid];
      float m = fmaxf(s0, s1);
      float e0 = expf(s0 - m), e1 = expf(s1 - m);
      float inv = 1.0f / (e0 + e1);
      W0 += e0 * inv; W1 += e1 * inv;
    }
    wmix[0][tid] = W0 * 0.25f;
    wmix[1][tid] = W1 * 0.25f;
  }
  __syncthreads();
  // nxt -> M0
  for (int rep = 0; rep < 16; ++rep) {
    int idx = rep * 256 + tid; int i = idx >> 6, d = idx & 63;
    M0[i][d] = wmix[0][i] * G0[i][d] + wmix[1][i] * G1[i][d];
  }
  __syncthreads();
  // GRU gates u, r  (xs = [nxt | enc])
  float uu[16], encv[16];
  {
    float au[16], ar[16];
#pragma unroll
    for (int jj = 0; jj < 16; ++jj) { au[jj] = bu[jb + jj]; ar[jj] = br[jb + jj]; }
    for (int kk = 0; kk < DD; ++kk) {
      float x = M0[lane][kk];
#pragma unroll
      for (int jj = 0; jj < 16; ++jj) {
        au[jj] = fmaf(x, wu[kk * DD + jb + jj], au[jj]);
        ar[jj] = fmaf(x, wr[kk * DD + jb + jj], ar[jj]);
      }
    }
    for (int kk = 0; kk < DD; ++kk) {
      float x = E[lane][kk];
#pragma unroll
      for (int jj = 0; jj < 16; ++jj) {
        au[jj] = fmaf(x, wu[(DD + kk) * DD + jb + jj], au[jj]);
        ar[jj] = fmaf(x, wr[(DD + kk) * DD + jb + jj], ar[jj]);
      }
    }
#pragma unroll
    for (int jj = 0; jj < 16; ++jj) {
      uu[jj] = sigmoidf_(au[jj]);
      G0[lane][jb + jj] = sigmoidf_(ar[jj]);   // r
      encv[jj] = E[lane][jb + jj];
    }
  }
  __syncthreads();
  // E <- r * enc
  for (int rep = 0; rep < 16; ++rep) {
    int idx = rep * 256 + tid; int i = idx >> 6, d = idx & 63;
    E[i][d] *= G0[i][d];
  }
  __syncthreads();
  // candidate c, output
  {
    float ac[16];
#pragma unroll
    for (int jj = 0; jj < 16; ++jj) ac[jj] = bc[jb + jj];
    for (int kk = 0; kk < DD; ++kk) {
      float x = M0[lane][kk];
#pragma unroll
      for (int jj = 0; jj < 16; ++jj) ac[jj] = fmaf(x, wc[kk * DD + jb + jj], ac[jj]);
    }
    for (int kk = 0; kk < DD; ++kk) {
      float x = E[lane][kk];
#pragma unroll
      for (int jj = 0; jj < 16; ++jj) ac[jj] = fmaf(x, wc[(DD + kk) * DD + jb + jj], ac[jj]);
    }
#pragma unroll
    for (int jj = 0; jj < 16; ++jj) {
      float cc = tanhf(ac[jj]);
      float eo = uu[jj] * encv[jj] + (1.0f - uu[jj]) * cc;
      encOut[(size_t)(tile0 + lane) * DD + jb + jj] = eo;
      G1[lane][jb + jj] = eo;
    }
  }
  if (do_decode) {
    __syncthreads();
    float hd[16], hq[16];
#pragma unroll
    for (int jj = 0; jj < 16; ++jj) { hd[jj] = db0[jb + jj]; hq[jj] = ub0[jb + jj]; }
    for (int kk = 0; kk < DD; ++kk) {
      float x = G1[lane][kk];
#pragma unroll
      for (int jj = 0; jj < 16; ++jj) {
        hd[jj] = fmaf(x, dw0[kk * DD + jb + jj], hd[jj]);
        hq[jj] = fmaf(x, uw0[kk * DD + jb + jj], hq[jj]);
      }
    }
    float p = 0.0f, q = 0.0f;
#pragma unroll
    for (int jj = 0; jj < 16; ++jj) { p += hd[jj] * dw1[jb + jj]; q += hq[jj] * uw1[jb + jj]; }
    scred[w][0][lane] = p; scred[w][1][lane] = q;
    __syncthreads();
    if (tid < 64) {
      pred[tile0 + tid] = scred[0][0][tid] + scred[1][0][tid] + scred[2][0][tid] + scred[3][0][tid] + db1[0];
    } else if (tid < 128) {
      int i = tid - 64;
      dualp[tile0 + i] = scred[0][1][i] + scred[1][1][i] + scred[2][1][i] + scred[3][1][i] + ub1[0];
    }
  }
}

// ------- fused: sparsemax (fixed-point tau) + CSC scatter + dual edge cost -------
__global__ void __launch_bounds__(256) k_primal_dual(
    const int* __restrict__ nb_cols, const int* __restrict__ nb_cnt,
    const float* __restrict__ pred, const float* __restrict__ dualp,
    const float* __restrict__ dem,
    float* __restrict__ rowsum,
    int* __restrict__ col_cnt, int* __restrict__ col_rows, float* __restrict__ col_vals,
    float* __restrict__ out) {
  __shared__ float bacc[BB];
  if (threadIdx.x < BB) bacc[threadIdx.x] = 0.0f;
  __syncthreads();
  int w = threadIdx.x >> 6, lane = threadIdx.x & 63;
  int row = blockIdx.x * 4 + w;
  int b = row / VV;
  int n = nb_cnt[row];
  int c = (lane < n) ? nb_cols[(size_t)row * CAP + lane] : 0;
  const float* predB = pred + (size_t)b * VV;
  const float* dualB = dualp + (size_t)b * VV;
  float z = (lane < n) ? predB[c] : -1e30f;
  float tau = 0.0f;
  if (n > 0) {
    bool in = (lane < n);
    for (int it = 0; it < 64; ++it) {
      float s = wredsum(in ? z : 0.0f);
      int cnt = (int)__popcll(__ballot(in));
      tau = (s - 1.0f) / (float)cnt;
      bool nin = (z > tau);
      if (__ballot(nin) == __ballot(in)) break;
      in = nin;
    }
  }
  float pv = (lane < n) ? fmaxf(z - tau, 0.0f) : 0.0f;
  float s2 = wredsum(pv * pv);
  if (lane == 0) rowsum[row] = s2;
  if (pv > 0.0f) {
    int g = b * VV + c;
    int j = atomicAdd(&col_cnt[g], 1);
    if (j < CAP) {
      col_rows[(size_t)g * CAP + j] = row - b * VV;
      col_vals[(size_t)g * CAP + j] = pv;
    }
  }
  float du = dualp[row];
  float es = 0.0f;
  if (lane < n) {
    float dd = du - dualB[c];
    float f = 0.0f, acm = 0.0f;
#pragma unroll
    for (int t = 0; t < 8; ++t) {
      float look = f - 0.9f * acm;
      float grad = 2.0f * look - dd;
      acm = 0.9f * acm + 0.1f * grad;
      f = fmaxf(f - acm, 0.0f);
    }
    es = f * f - dd * f;
  }
  float contrib = -es;
  if (lane == 0) contrib += du * dem[row];
  float ws_ = wredsum(contrib);
  if (lane == 0) atomicAdd(&bacc[b], ws_);
  __syncthreads();
  if (threadIdx.x < BB) {
    float t = bacc[threadIdx.x];
    if (t != 0.0f) atomicAdd(&out[threadIdx.x], t);
  }
}

// ------- fused flow iterations (per-graph block) + flow cost -------
__global__ void __launch_bounds__(1024) k_flow(
    const int* __restrict__ col_cnt, const int* __restrict__ col_rows,
    const float* __restrict__ col_vals, const float* __restrict__ dem,
    const float* __restrict__ rowsum, float* __restrict__ out) {
  __shared__ float aS[VV];
  __shared__ float red[16];
  int b = blockIdx.x;
  int tid = threadIdx.x;
  const float* demB = dem + (size_t)b * VV;
  for (int v = tid; v < VV; v += 1024) aS[v] = fmaxf(-demB[v], 0.0f);
  __syncthreads();
  for (int t = 0; t < 7; ++t) {
    float nv0 = 0.0f, nv1 = 0.0f;
    {
      int v = tid;
      if (v < VV) {
        int g = b * VV + v;
        int n = col_cnt[g]; if (n > CAP) n = CAP;
        const int* cr = col_rows + (size_t)g * CAP;
        const float* cv = col_vals + (size_t)g * CAP;
        float acc = 0.0f;
        for (int j = 0; j < n; ++j) acc += cv[j] * aS[cr[j]];
        nv0 = fmaxf(acc - demB[v], 0.0f);
      }
      v = tid + 1024;
      if (v < VV) {
        int g = b * VV + v;
        int n = col_cnt[g]; if (n > CAP) n = CAP;
        const int* cr = col_rows + (size_t)g * CAP;
        const float* cv = col_vals + (size_t)g * CAP;
        float acc = 0.0f;
        for (int j = 0; j < n; ++j) acc += cv[j] * aS[cr[j]];
        nv1 = fmaxf(acc - demB[v], 0.0f);
      }
    }
    __syncthreads();
    if (tid < VV) aS[tid] = nv0;
    if (tid + 1024 < VV) aS[tid + 1024] = nv1;
    __syncthreads();
  }
  float fc = 0.0f;
  for (int v = tid; v < VV; v += 1024) { float a = aS[v]; fc += a * a * rowsum[b * VV + v]; }
  fc = wredsum(fc);
  int wid = tid >> 6, lane = tid & 63;
  if (lane == 0) red[wid] = fc;
  __syncthreads();
  if (tid == 0) {
    float s = 0.0f;
#pragma unroll
    for (int i = 0; i < 16; ++i) s += red[i];
    atomicAdd(&out[b], s);
  }
}

extern "C" void kernel_launch(void* const* d_in, const int* in_sizes, int n_in,
                              void* d_out, int out_size, void* d_ws, size_t ws_size,
                              hipStream_t stream) {
  const float* feat   = (const float*)d_in[0];
  const float* emb    = (const float*)d_in[1];
  const float* dem    = (const float*)d_in[2];
  const float* nb     = (const float*)d_in[4];   // [K,B,V,V]
  const float* enc_w0 = (const float*)d_in[5];
  const float* enc_b0 = (const float*)d_in[6];
  const float* enc_w1 = (const float*)d_in[7];
  const float* enc_b1 = (const float*)d_in[8];
  const float* agg_w  = (const float*)d_in[9];
  const float* agg_b  = (const float*)d_in[10];
  const float* att_w  = (const float*)d_in[11];
  const float* att_b  = (const float*)d_in[12];
  const float* att_v  = (const float*)d_in[13];
  const float* gru_wu = (const float*)d_in[14];
  const float* gru_bu = (const float*)d_in[15];
  const float* gru_wr = (const float*)d_in[16];
  const float* gru_br = (const float*)d_in[17];
  const float* gru_wc = (const float*)d_in[18];
  const float* gru_bc = (const float*)d_in[19];
  const float* dec_w0 = (const float*)d_in[20];
  const float* dec_b0 = (const float*)d_in[21];
  const float* dec_w1 = (const float*)d_in[22];
  const float* dec_b1 = (const float*)d_in[23];
  const float* dual_w0= (const float*)d_in[24];
  const float* dual_b0= (const float*)d_in[25];
  const float* dual_w1= (const float*)d_in[26];
  const float* dual_b1= (const float*)d_in[27];
  float* out = (float*)d_out;

  float* ws = (float*)d_ws;
  float* enc0     = ws;                              // NROW*DD
  float* enc1     = enc0 + (size_t)NROW * DD;
  float* msg      = enc1 + (size_t)NROW * DD;        // NKROW*DD
  float* pred     = msg + (size_t)NKROW * DD;
  float* dualp    = pred + NROW;
  float* rowsum   = dualp + NROW;
  float* col_vals = rowsum + NROW;                   // NROW*CAP
  int* col_cnt  = (int*)(col_vals + (size_t)NROW * CAP);
  int* nb_cnt   = col_cnt + NROW;                    // NKROW
  int* col_rows = nb_cnt + NKROW;                    // NROW*CAP
  int* nb_cols  = col_rows + (size_t)NROW * CAP;

  (void)in_sizes; (void)n_in; (void)ws_size;

  hipMemsetAsync(out, 0, (size_t)out_size * sizeof(float), stream);
  hipMemsetAsync(col_cnt, 0, (size_t)NROW * sizeof(int), stream);

  k_nbcsr<<<NKROW / 4, 256, 0, stream>>>(nb, nb_cols, nb_cnt);
  k_encoder<<<NROW / 64, 256, 0, stream>>>(emb, feat, enc_w0, enc_b0, enc_w1, enc_b1, enc0);

  const float* encIn = enc0;
  float* encOut = enc1;
  for (int l = 0; l < 2; ++l) {
    k_gather<<<NKROW / 4, 256, 0, stream>>>(nb_cols, nb_cnt, encIn, msg);
    k_layer<<<NROW / 64, 256, 0, stream>>>(msg, encIn,
                                           agg_w, agg_b, att_w, att_b, att_v,
                                           gru_wu, gru_bu, gru_wr, gru_br, gru_wc, gru_bc,
                                           encOut,
                                           (l == 1) ? 1 : 0,
                                           dec_w0, dec_b0, dec_w1, dec_b1,
                                           dual_w0, dual_b0, dual_w1, dual_b1, pred, dualp);
    const float* t = encIn; encIn = encOut; encOut = (float*)t;
  }

  k_primal_dual<<<NROW / 4, 256, 0, stream>>>(nb_cols, nb_cnt, pred, dualp, dem,
                                              rowsum, col_cnt, col_rows, col_vals, out);
  k_flow<<<BB, 1024, 0, stream>>>(col_cnt, col_rows, col_vals, dem, rowsum, out);
}

// Round 5
// 641.314 us; speedup vs baseline: 1.4374x; 1.1671x over previous
//
#include <hip/hip_runtime.h>

#define BB 8
#define VV 1200
#define DD 64
#define KH 2     // hops
#define NH 4     // heads
#define CAP 64        // hop1 cap
#define NB2CAP 384    // hop2 cap
#define NROW (BB*VV)          // 9600
#define NKROW (KH*BB*VV)      // 19200

__device__ __forceinline__ float wredsum(float v) {
#pragma unroll
  for (int o = 32; o > 0; o >>= 1) v += __shfl_xor(v, o, 64);
  return v;
}

// fast tanh via hw exp: tanh(x) = 1 - 2/(e^{2x}+1).  e->inf => 1, e->0 => -1 (no NaN)
__device__ __forceinline__ float tanh_f(float x) {
  float e = __expf(2.0f * x);
  return 1.0f - 2.0f / (e + 1.0f);
}
__device__ __forceinline__ float sigmoid_f(float x) { return 1.0f / (1.0f + __expf(-x)); }

__device__ __forceinline__ size_t nb_base(int row) {
  return (row < NROW) ? (size_t)row * CAP
                      : (size_t)NROW * CAP + (size_t)(row - NROW) * NB2CAP;
}

// ---------------- build CSR of binary neighborhoods (dense 92MB read once) ----------------
__global__ void __launch_bounds__(256) k_nbcsr(
    const float* __restrict__ nb,
    int* __restrict__ nb_cols, int* __restrict__ nb_cnt) {
  int wid = threadIdx.x >> 6, lane = threadIdx.x & 63;
  int row = blockIdx.x * 4 + wid;
  if (row >= NKROW) return;
  const float* nbrow = nb + (size_t)row * VV;
  size_t base = nb_base(row);
  int cap = (row < NROW) ? CAP : NB2CAP;
  unsigned long long ltmask = (lane == 0) ? 0ull : ((1ull << lane) - 1ull);
  int cnt = 0;
  for (int b0 = 0; b0 < VV; b0 += 64) {
    int v = b0 + lane;
    float val = (v < VV) ? nbrow[v] : 0.0f;
    unsigned long long mask = __ballot(val != 0.0f);
    int off = cnt + __popcll(mask & ltmask);
    if (val != 0.0f && off < cap) nb_cols[base + off] = v;
    cnt += __popcll(mask);
  }
  if (lane == 0) nb_cnt[row] = (cnt > cap) ? cap : cnt;
}

// ---------------- encoder: GEMM-tiled, 64 rows/block ----------------
__global__ void __launch_bounds__(256) k_encoder(
    const float* __restrict__ emb, const float* __restrict__ feat,
    const float* __restrict__ w0, const float* __restrict__ b0,
    const float* __restrict__ w1, const float* __restrict__ b1,
    float* __restrict__ enc0) {
  __shared__ float xT[64][25];
  __shared__ float hT[64][65];
  int tid = threadIdx.x, lane = tid & 63;
  int tile0 = blockIdx.x * 64;
  for (int rep = 0; rep < 4; ++rep) {
    int idx = rep * 256 + tid; int i = idx >> 4, d = idx & 15;
    xT[i][d] = emb[(size_t)(tile0 + i) * 16 + d];
  }
  for (int rep = 0; rep < 2; ++rep) {
    int idx = rep * 256 + tid; int i = idx >> 3, d = idx & 7;
    xT[i][16 + d] = feat[(size_t)(tile0 + i) * 8 + d];
  }
  __syncthreads();
  int jb = __builtin_amdgcn_readfirstlane((tid >> 6) * 16);
  float acc[16];
#pragma unroll
  for (int jj = 0; jj < 16; ++jj) acc[jj] = b0[jb + jj];
  for (int kk = 0; kk < 24; ++kk) {
    float x = xT[lane][kk];
#pragma unroll
    for (int jj = 0; jj < 16; ++jj) acc[jj] = fmaf(x, w0[kk * DD + jb + jj], acc[jj]);
  }
#pragma unroll
  for (int jj = 0; jj < 16; ++jj) hT[lane][jb + jj] = tanh_f(acc[jj]);
  __syncthreads();
  float a2[16];
#pragma unroll
  for (int jj = 0; jj < 16; ++jj) a2[jj] = b1[jb + jj];
  for (int kk = 0; kk < DD; ++kk) {
    float x = hT[lane][kk];
#pragma unroll
    for (int jj = 0; jj < 16; ++jj) a2[jj] = fmaf(x, w1[kk * DD + jb + jj], a2[jj]);
  }
#pragma unroll
  for (int jj = 0; jj < 16; ++jj) {
    enc0[(size_t)(tile0 + lane) * DD + jb + jj] = tanh_f(a2[jj]);
  }
}

// ---------------- gather: wave per row, float4 lanes, deep ILP ----------------
__global__ void __launch_bounds__(256) k_gather(
    const int* __restrict__ nb_cols, const int* __restrict__ nb_cnt,
    const float* __restrict__ encIn, float* __restrict__ msg) {
  int w = threadIdx.x >> 6, lane = threadIdx.x & 63;
  int row = blockIdx.x * 4 + w;           // [0, NKROW)
  int k = (row >= NROW) ? 1 : 0;
  int bv = row - k * NROW;
  int b = bv / VV;
  const float4* enc4 = (const float4*)(encIn + (size_t)b * VV * DD);
  const int* cols = nb_cols + nb_base(row);
  int n = nb_cnt[row];
  int sub = lane >> 4, q = lane & 15;
  float ax = 0.0f, ay = 0.0f, az = 0.0f, aw = 0.0f;
  int j = 0;
  for (; j + 16 <= n; j += 16) {
    int c0 = cols[j + sub];
    int c1 = cols[j + 4 + sub];
    int c2 = cols[j + 8 + sub];
    int c3 = cols[j + 12 + sub];
    float4 v0 = enc4[(size_t)c0 * 16 + q];
    float4 v1 = enc4[(size_t)c1 * 16 + q];
    float4 v2 = enc4[(size_t)c2 * 16 + q];
    float4 v3 = enc4[(size_t)c3 * 16 + q];
    ax += (v0.x + v1.x) + (v2.x + v3.x);
    ay += (v0.y + v1.y) + (v2.y + v3.y);
    az += (v0.z + v1.z) + (v2.z + v3.z);
    aw += (v0.w + v1.w) + (v2.w + v3.w);
  }
  for (; j < n; j += 4) {
    int idx = j + sub;
    if (idx < n) {
      float4 v = enc4[(size_t)cols[idx] * 16 + q];
      ax += v.x; ay += v.y; az += v.z; aw += v.w;
    }
  }
#pragma unroll
  for (int o = 16; o < 64; o <<= 1) {
    ax += __shfl_xor(ax, o, 64);
    ay += __shfl_xor(ay, o, 64);
    az += __shfl_xor(az, o, 64);
    aw += __shfl_xor(aw, o, 64);
  }
  if (lane < 16) {
    float inv = 1.0f / fmaxf((float)n, 1.0f);
    float4 r; r.x = ax * inv; r.y = ay * inv; r.z = az * inv; r.w = aw * inv;
    ((float4*)(msg + (size_t)row * DD))[q] = r;
  }
}

// ---------------- agg GEMM + attention scores: per-hop 64-row tiles, 8 waves ----------------
__global__ void __launch_bounds__(512) k_aggatt(
    const float* __restrict__ msg,
    const float* __restrict__ agg_w, const float* __restrict__ agg_b,
    const float* __restrict__ att_w, const float* __restrict__ att_b,
    const float* __restrict__ att_v,
    float* __restrict__ agg, float* __restrict__ scores) {
  __shared__ float M[64][65];
  __shared__ float G[64][65];
  __shared__ float scp[8][NH][64];
  int tid = threadIdx.x, w = tid >> 6, lane = tid & 63;
  int tile0 = blockIdx.x * 64;            // [0, NKROW)
  int k = tile0 / NROW;                   // uniform per block
  int bv0 = tile0 - k * NROW;
  for (int rep = 0; rep < 8; ++rep) {
    int idx = rep * 512 + tid; int i = idx >> 6, d = idx & 63;
    M[i][d] = msg[(size_t)(tile0 + i) * DD + d];
  }
  __syncthreads();
  int jb = __builtin_amdgcn_readfirstlane(w * 8);
  const float* W = agg_w + (size_t)k * DD * DD;
  float a[8];
#pragma unroll
  for (int jj = 0; jj < 8; ++jj) a[jj] = agg_b[k * DD + jb + jj];
  for (int kk = 0; kk < DD; ++kk) {
    float x = M[lane][kk];
#pragma unroll
    for (int jj = 0; jj < 8; ++jj) a[jj] = fmaf(x, W[kk * DD + jb + jj], a[jj]);
  }
#pragma unroll
  for (int jj = 0; jj < 8; ++jj) G[lane][jb + jj] = tanh_f(a[jj]);
  __syncthreads();
  // coalesced global write of agg tile
  for (int rep = 0; rep < 8; ++rep) {
    int idx = rep * 512 + tid; int i = idx >> 6, d = idx & 63;
    agg[(size_t)(tile0 + i) * DD + d] = G[i][d];
  }
  // attention scores per head
  for (int h = 0; h < NH; ++h) {
    const float* Wh = att_w + (size_t)h * DD * DD;
    float a2[8];
#pragma unroll
    for (int jj = 0; jj < 8; ++jj) a2[jj] = att_b[h * DD + jb + jj];
    for (int kk = 0; kk < DD; ++kk) {
      float x = G[lane][kk];
#pragma unroll
      for (int jj = 0; jj < 8; ++jj) a2[jj] = fmaf(x, Wh[kk * DD + jb + jj], a2[jj]);
    }
    float p = 0.0f;
#pragma unroll
    for (int jj = 0; jj < 8; ++jj) p += tanh_f(a2[jj]) * att_v[h * DD + jb + jj];
    scp[w][h][lane] = p;
  }
  __syncthreads();
  if (tid < NH * 64) {
    int h = tid >> 6, i = tid & 63;
    float s = 0.0f;
#pragma unroll
    for (int ww = 0; ww < 8; ++ww) s += scp[ww][h][i];
    scores[(size_t)(h * KH + k) * NROW + bv0 + i] = s;
  }
}

// ---------------- attention mix + GRU (+ fused decode), 64 rows, 8 waves ----------------
__global__ void __launch_bounds__(512) k_gru(
    const float* __restrict__ encIn, const float* __restrict__ agg,
    const float* __restrict__ scores,
    const float* __restrict__ wu, const float* __restrict__ bu,
    const float* __restrict__ wr, const float* __restrict__ br,
    const float* __restrict__ wc, const float* __restrict__ bc,
    float* __restrict__ encOut,
    int do_decode,
    const float* __restrict__ dw0, const float* __restrict__ db0,
    const float* __restrict__ dw1, const float* __restrict__ db1,
    const float* __restrict__ uw0, const float* __restrict__ ub0,
    const float* __restrict__ uw1, const float* __restrict__ ub1,
    float* __restrict__ pred, float* __restrict__ dualp) {
  __shared__ float X[64][129];     // [row][0..63]=nxt, [64..127]=enc then r*enc
  __shared__ float R[64][65];      // r gate, later reused as output tile
  __shared__ float wmix[2][64];
  __shared__ float scred[8][2][64];
  int tid = threadIdx.x, w = tid >> 6, lane = tid & 63;
  int tile0 = blockIdx.x * 64;
  for (int rep = 0; rep < 8; ++rep) {
    int idx = rep * 512 + tid; int i = idx >> 6, d = idx & 63;
    X[i][64 + d] = encIn[(size_t)(tile0 + i) * DD + d];
  }
  if (tid < 64) {
    int i = tid;
    float W0 = 0.0f, W1 = 0.0f;
#pragma unroll
    for (int h = 0; h < NH; ++h) {
      float s0 = scores[(size_t)(h * KH + 0) * NROW + tile0 + i];
      float s1 = scores[(size_t)(h * KH + 1) * NROW + tile0 + i];
      float m = fmaxf(s0, s1);
      float e0 = __expf(s0 - m), e1 = __expf(s1 - m);
      float inv = 1.0f / (e0 + e1);
      W0 += e0 * inv; W1 += e1 * inv;
    }
    wmix[0][i] = W0 * 0.25f;
    wmix[1][i] = W1 * 0.25f;
  }
  __syncthreads();
  for (int rep = 0; rep < 8; ++rep) {
    int idx = rep * 512 + tid; int i = idx >> 6, d = idx & 63;
    float a0 = agg[(size_t)(tile0 + i) * DD + d];
    float a1 = agg[(size_t)(NROW + tile0 + i) * DD + d];
    X[i][d] = wmix[0][i] * a0 + wmix[1][i] * a1;
  }
  __syncthreads();
  int jb = __builtin_amdgcn_readfirstlane(w * 8);
  // u, r gates over xs=[nxt|enc]
  float au[8], ar[8];
#pragma unroll
  for (int jj = 0; jj < 8; ++jj) { au[jj] = bu[jb + jj]; ar[jj] = br[jb + jj]; }
  for (int kk = 0; kk < 2 * DD; ++kk) {
    float x = X[lane][kk];
#pragma unroll
    for (int jj = 0; jj < 8; ++jj) {
      au[jj] = fmaf(x, wu[kk * DD + jb + jj], au[jj]);
      ar[jj] = fmaf(x, wr[kk * DD + jb + jj], ar[jj]);
    }
  }
  float uu[8], encv[8];
#pragma unroll
  for (int jj = 0; jj < 8; ++jj) {
    uu[jj] = sigmoid_f(au[jj]);
    R[lane][jb + jj] = sigmoid_f(ar[jj]);
    encv[jj] = X[lane][64 + jb + jj];     // read before overwrite
  }
  __syncthreads();
  for (int rep = 0; rep < 8; ++rep) {
    int idx = rep * 512 + tid; int i = idx >> 6, d = idx & 63;
    X[i][64 + d] *= R[i][d];
  }
  __syncthreads();
  // candidate
  float ac[8];
#pragma unroll
  for (int jj = 0; jj < 8; ++jj) ac[jj] = bc[jb + jj];
  for (int kk = 0; kk < 2 * DD; ++kk) {
    float x = X[lane][kk];
#pragma unroll
    for (int jj = 0; jj < 8; ++jj) ac[jj] = fmaf(x, wc[kk * DD + jb + jj], ac[jj]);
  }
#pragma unroll
  for (int jj = 0; jj < 8; ++jj) {
    float cc = tanh_f(ac[jj]);
    float eo = uu[jj] * encv[jj] + (1.0f - uu[jj]) * cc;
    encOut[(size_t)(tile0 + lane) * DD + jb + jj] = eo;
    R[lane][jb + jj] = eo;                // reuse R as output tile (X-only reads in flight)
  }
  if (do_decode) {
    __syncthreads();
    float hd[8], hq[8];
#pragma unroll
    for (int jj = 0; jj < 8; ++jj) { hd[jj] = db0[jb + jj]; hq[jj] = ub0[jb + jj]; }
    for (int kk = 0; kk < DD; ++kk) {
      float x = R[lane][kk];
#pragma unroll
      for (int jj = 0; jj < 8; ++jj) {
        hd[jj] = fmaf(x, dw0[kk * DD + jb + jj], hd[jj]);
        hq[jj] = fmaf(x, uw0[kk * DD + jb + jj], hq[jj]);
      }
    }
    float p = 0.0f, q = 0.0f;
#pragma unroll
    for (int jj = 0; jj < 8; ++jj) { p += hd[jj] * dw1[jb + jj]; q += hq[jj] * uw1[jb + jj]; }
    scred[w][0][lane] = p; scred[w][1][lane] = q;
    __syncthreads();
    if (tid < 64) {
      float s = db1[0];
#pragma unroll
      for (int ww = 0; ww < 8; ++ww) s += scred[ww][0][tid];
      pred[tile0 + tid] = s;
    } else if (tid < 128) {
      int i = tid - 64;
      float s = ub1[0];
#pragma unroll
      for (int ww = 0; ww < 8; ++ww) s += scred[ww][1][i];
      dualp[tile0 + i] = s;
    }
  }
}

// ------- fused: sparsemax (fixed-point tau) + CSC scatter + dual edge cost -------
__global__ void __launch_bounds__(256) k_primal_dual(
    const int* __restrict__ nb_cols, const int* __restrict__ nb_cnt,
    const float* __restrict__ pred, const float* __restrict__ dualp,
    const float* __restrict__ dem,
    float* __restrict__ rowsum,
    int* __restrict__ col_cnt, int* __restrict__ col_rows, float* __restrict__ col_vals,
    float* __restrict__ out) {
  __shared__ float bacc[BB];
  if (threadIdx.x < BB) bacc[threadIdx.x] = 0.0f;
  __syncthreads();
  int w = threadIdx.x >> 6, lane = threadIdx.x & 63;
  int row = blockIdx.x * 4 + w;
  int b = row / VV;
  int n = nb_cnt[row];
  int c = (lane < n) ? nb_cols[(size_t)row * CAP + lane] : 0;
  const float* predB = pred + (size_t)b * VV;
  const float* dualB = dualp + (size_t)b * VV;
  float z = (lane < n) ? predB[c] : -1e30f;
  float tau = 0.0f;
  if (n > 0) {
    bool in = (lane < n);
    for (int it = 0; it < 64; ++it) {
      float s = wredsum(in ? z : 0.0f);
      int cnt = (int)__popcll(__ballot(in));
      tau = (s - 1.0f) / (float)cnt;
      bool nin = (z > tau);
      if (__ballot(nin) == __ballot(in)) break;
      in = nin;
    }
  }
  float pv = (lane < n) ? fmaxf(z - tau, 0.0f) : 0.0f;
  float s2 = wredsum(pv * pv);
  if (lane == 0) rowsum[row] = s2;
  if (pv > 0.0f) {
    int g = b * VV + c;
    int j = atomicAdd(&col_cnt[g], 1);
    if (j < CAP) {
      col_rows[(size_t)g * CAP + j] = row - b * VV;
      col_vals[(size_t)g * CAP + j] = pv;
    }
  }
  float du = dualp[row];
  float es = 0.0f;
  if (lane < n) {
    float dd = du - dualB[c];
    float f = 0.0f, acm = 0.0f;
#pragma unroll
    for (int t = 0; t < 8; ++t) {
      float look = f - 0.9f * acm;
      float grad = 2.0f * look - dd;
      acm = 0.9f * acm + 0.1f * grad;
      f = fmaxf(f - acm, 0.0f);
    }
    es = f * f - dd * f;
  }
  float contrib = -es;
  if (lane == 0) contrib += du * dem[row];
  float ws_ = wredsum(contrib);
  if (lane == 0) atomicAdd(&bacc[b], ws_);
  __syncthreads();
  if (threadIdx.x < BB) {
    float t = bacc[threadIdx.x];
    if (t != 0.0f) atomicAdd(&out[threadIdx.x], t);
  }
}

// ------- fused flow iterations (per-graph block) + flow cost -------
__global__ void __launch_bounds__(1024) k_flow(
    const int* __restrict__ col_cnt, const int* __restrict__ col_rows,
    const float* __restrict__ col_vals, const float* __restrict__ dem,
    const float* __restrict__ rowsum, float* __restrict__ out) {
  __shared__ float aS[VV];
  __shared__ float red[16];
  int b = blockIdx.x;
  int tid = threadIdx.x;
  const float* demB = dem + (size_t)b * VV;
  for (int v = tid; v < VV; v += 1024) aS[v] = fmaxf(-demB[v], 0.0f);
  __syncthreads();
  for (int t = 0; t < 7; ++t) {
    float nv0 = 0.0f, nv1 = 0.0f;
    {
      int v = tid;
      if (v < VV) {
        int g = b * VV + v;
        int n = col_cnt[g]; if (n > CAP) n = CAP;
        const int* cr = col_rows + (size_t)g * CAP;
        const float* cv = col_vals + (size_t)g * CAP;
        float acc = 0.0f;
        for (int j = 0; j < n; ++j) acc += cv[j] * aS[cr[j]];
        nv0 = fmaxf(acc - demB[v], 0.0f);
      }
      v = tid + 1024;
      if (v < VV) {
        int g = b * VV + v;
        int n = col_cnt[g]; if (n > CAP) n = CAP;
        const int* cr = col_rows + (size_t)g * CAP;
        const float* cv = col_vals + (size_t)g * CAP;
        float acc = 0.0f;
        for (int j = 0; j < n; ++j) acc += cv[j] * aS[cr[j]];
        nv1 = fmaxf(acc - demB[v], 0.0f);
      }
    }
    __syncthreads();
    if (tid < VV) aS[tid] = nv0;
    if (tid + 1024 < VV) aS[tid + 1024] = nv1;
    __syncthreads();
  }
  float fc = 0.0f;
  for (int v = tid; v < VV; v += 1024) { float a = aS[v]; fc += a * a * rowsum[b * VV + v]; }
  fc = wredsum(fc);
  int wid = tid >> 6, lane = tid & 63;
  if (lane == 0) red[wid] = fc;
  __syncthreads();
  if (tid == 0) {
    float s = 0.0f;
#pragma unroll
    for (int i = 0; i < 16; ++i) s += red[i];
    atomicAdd(&out[b], s);
  }
}

extern "C" void kernel_launch(void* const* d_in, const int* in_sizes, int n_in,
                              void* d_out, int out_size, void* d_ws, size_t ws_size,
                              hipStream_t stream) {
  const float* feat   = (const float*)d_in[0];
  const float* emb    = (const float*)d_in[1];
  const float* dem    = (const float*)d_in[2];
  const float* nb     = (const float*)d_in[4];   // [K,B,V,V]
  const float* enc_w0 = (const float*)d_in[5];
  const float* enc_b0 = (const float*)d_in[6];
  const float* enc_w1 = (const float*)d_in[7];
  const float* enc_b1 = (const float*)d_in[8];
  const float* agg_w  = (const float*)d_in[9];
  const float* agg_b  = (const float*)d_in[10];
  const float* att_w  = (const float*)d_in[11];
  const float* att_b  = (const float*)d_in[12];
  const float* att_v  = (const float*)d_in[13];
  const float* gru_wu = (const float*)d_in[14];
  const float* gru_bu = (const float*)d_in[15];
  const float* gru_wr = (const float*)d_in[16];
  const float* gru_br = (const float*)d_in[17];
  const float* gru_wc = (const float*)d_in[18];
  const float* gru_bc = (const float*)d_in[19];
  const float* dec_w0 = (const float*)d_in[20];
  const float* dec_b0 = (const float*)d_in[21];
  const float* dec_w1 = (const float*)d_in[22];
  const float* dec_b1 = (const float*)d_in[23];
  const float* dual_w0= (const float*)d_in[24];
  const float* dual_b0= (const float*)d_in[25];
  const float* dual_w1= (const float*)d_in[26];
  const float* dual_b1= (const float*)d_in[27];
  float* out = (float*)d_out;

  float* ws = (float*)d_ws;
  float* enc0     = ws;                              // NROW*DD
  float* enc1     = enc0 + (size_t)NROW * DD;
  float* msg      = enc1 + (size_t)NROW * DD;        // NKROW*DD
  float* aggbuf   = msg + (size_t)NKROW * DD;        // NKROW*DD
  float* scores   = aggbuf + (size_t)NKROW * DD;     // NH*KH*NROW
  float* pred     = scores + (size_t)NH * KH * NROW;
  float* dualp    = pred + NROW;
  float* rowsum   = dualp + NROW;
  float* col_vals = rowsum + NROW;                   // NROW*CAP
  int* col_cnt  = (int*)(col_vals + (size_t)NROW * CAP);
  int* nb_cnt   = col_cnt + NROW;                    // NKROW
  int* col_rows = nb_cnt + NKROW;                    // NROW*CAP
  int* nb_cols  = col_rows + (size_t)NROW * CAP;

  (void)in_sizes; (void)n_in; (void)ws_size;

  hipMemsetAsync(out, 0, (size_t)out_size * sizeof(float), stream);
  hipMemsetAsync(col_cnt, 0, (size_t)NROW * sizeof(int), stream);

  k_nbcsr<<<NKROW / 4, 256, 0, stream>>>(nb, nb_cols, nb_cnt);
  k_encoder<<<NROW / 64, 256, 0, stream>>>(emb, feat, enc_w0, enc_b0, enc_w1, enc_b1, enc0);

  const float* encIn = enc0;
  float* encOut = enc1;
  for (int l = 0; l < 2; ++l) {
    k_gather<<<NKROW / 4, 256, 0, stream>>>(nb_cols, nb_cnt, encIn, msg);
    k_aggatt<<<NKROW / 64, 512, 0, stream>>>(msg, agg_w, agg_b, att_w, att_b, att_v,
                                             aggbuf, scores);
    k_gru<<<NROW / 64, 512, 0, stream>>>(encIn, aggbuf, scores,
                                         gru_wu, gru_bu, gru_wr, gru_br, gru_wc, gru_bc,
                                         encOut,
                                         (l == 1) ? 1 : 0,
                                         dec_w0, dec_b0, dec_w1, dec_b1,
                                         dual_w0, dual_b0, dual_w1, dual_b1, pred, dualp);
    const float* t = encIn; encIn = encOut; encOut = (float*)t;
  }

  k_primal_dual<<<NROW / 4, 256, 0, stream>>>(nb_cols, nb_cnt, pred, dualp, dem,
                                              rowsum, col_cnt, col_rows, col_vals, out);
  k_flow<<<BB, 1024, 0, stream>>>(col_cnt, col_rows, col_vals, dem, rowsum, out);
}

// Round 6
// 626.504 us; speedup vs baseline: 1.4714x; 1.0236x over previous
//
#include <hip/hip_runtime.h>

#define BB 8
#define VV 1200
#define DD 64
#define KH 2     // hops
#define NH 4     // heads
#define CAP 64        // hop1 cap
#define NB2CAP 384    // hop2 cap
#define NROW (BB*VV)          // 9600
#define NKROW (KH*BB*VV)      // 19200

__device__ __forceinline__ float wredsum(float v) {
#pragma unroll
  for (int o = 32; o > 0; o >>= 1) v += __shfl_xor(v, o, 64);
  return v;
}

// fast tanh via hw exp: tanh(x) = 1 - 2/(e^{2x}+1)
__device__ __forceinline__ float tanh_f(float x) {
  float e = __expf(2.0f * x);
  return 1.0f - 2.0f / (e + 1.0f);
}
__device__ __forceinline__ float sigmoid_f(float x) { return 1.0f / (1.0f + __expf(-x)); }

__device__ __forceinline__ size_t nb_base(int row) {
  return (row < NROW) ? (size_t)row * CAP
                      : (size_t)NROW * CAP + (size_t)(row - NROW) * NB2CAP;
}

// ---------------- build CSR of binary neighborhoods (dense 92MB read once) ----------------
__global__ void __launch_bounds__(256) k_nbcsr(
    const float* __restrict__ nb,
    int* __restrict__ nb_cols, int* __restrict__ nb_cnt) {
  int wid = threadIdx.x >> 6, lane = threadIdx.x & 63;
  int row = blockIdx.x * 4 + wid;
  if (row >= NKROW) return;
  const float* nbrow = nb + (size_t)row * VV;
  size_t base = nb_base(row);
  int cap = (row < NROW) ? CAP : NB2CAP;
  unsigned long long ltmask = (lane == 0) ? 0ull : ((1ull << lane) - 1ull);
  int cnt = 0;
  for (int b0 = 0; b0 < VV; b0 += 64) {
    int v = b0 + lane;
    float val = (v < VV) ? nbrow[v] : 0.0f;
    unsigned long long mask = __ballot(val != 0.0f);
    int off = cnt + __popcll(mask & ltmask);
    if (val != 0.0f && off < cap) nb_cols[base + off] = v;
    cnt += __popcll(mask);
  }
  if (lane == 0) nb_cnt[row] = (cnt > cap) ? cap : cnt;
}

// ---------------- encoder: 32 rows/block, thread=(row, 8-col group) ----------------
__global__ void __launch_bounds__(256) k_encoder(
    const float* __restrict__ emb, const float* __restrict__ feat,
    const float* __restrict__ w0, const float* __restrict__ b0,
    const float* __restrict__ w1, const float* __restrict__ b1,
    float* __restrict__ enc0) {
  __shared__ float xT[32][25];
  __shared__ float hT[32][65];
  int tid = threadIdx.x;
  int tile0 = blockIdx.x * 32;
  for (int rep = 0; rep < 2; ++rep) {
    int idx = rep * 256 + tid; int i = idx >> 4, d = idx & 15;
    xT[i][d] = emb[(size_t)(tile0 + i) * 16 + d];
  }
  { int i = tid >> 3, d = tid & 7; xT[i][16 + d] = feat[(size_t)(tile0 + i) * 8 + d]; }
  __syncthreads();
  int r = tid >> 3, cg = tid & 7;
  int c0 = cg * 8;
  float a[8];
#pragma unroll
  for (int jj = 0; jj < 8; ++jj) a[jj] = b0[c0 + jj];
  for (int kk = 0; kk < 24; ++kk) {
    float x = xT[r][kk];
    const float4* wr4 = (const float4*)(w0 + kk * DD + c0);
    float4 u0 = wr4[0], u1 = wr4[1];
    a[0] = fmaf(x, u0.x, a[0]); a[1] = fmaf(x, u0.y, a[1]);
    a[2] = fmaf(x, u0.z, a[2]); a[3] = fmaf(x, u0.w, a[3]);
    a[4] = fmaf(x, u1.x, a[4]); a[5] = fmaf(x, u1.y, a[5]);
    a[6] = fmaf(x, u1.z, a[6]); a[7] = fmaf(x, u1.w, a[7]);
  }
#pragma unroll
  for (int jj = 0; jj < 8; ++jj) hT[r][c0 + jj] = tanh_f(a[jj]);
  __syncthreads();
  float a2[8];
#pragma unroll
  for (int jj = 0; jj < 8; ++jj) a2[jj] = b1[c0 + jj];
#pragma unroll 4
  for (int kk = 0; kk < DD; ++kk) {
    float x = hT[r][kk];
    const float4* wr4 = (const float4*)(w1 + kk * DD + c0);
    float4 u0 = wr4[0], u1 = wr4[1];
    a2[0] = fmaf(x, u0.x, a2[0]); a2[1] = fmaf(x, u0.y, a2[1]);
    a2[2] = fmaf(x, u0.z, a2[2]); a2[3] = fmaf(x, u0.w, a2[3]);
    a2[4] = fmaf(x, u1.x, a2[4]); a2[5] = fmaf(x, u1.y, a2[5]);
    a2[6] = fmaf(x, u1.z, a2[6]); a2[7] = fmaf(x, u1.w, a2[7]);
  }
#pragma unroll
  for (int jj = 0; jj < 8; ++jj)
    enc0[(size_t)(tile0 + r) * DD + c0 + jj] = tanh_f(a2[jj]);
}

// ---------------- gather: wave per row, float4 lanes, deep ILP ----------------
__global__ void __launch_bounds__(256) k_gather(
    const int* __restrict__ nb_cols, const int* __restrict__ nb_cnt,
    const float* __restrict__ encIn, float* __restrict__ msg) {
  int w = threadIdx.x >> 6, lane = threadIdx.x & 63;
  int row = blockIdx.x * 4 + w;           // [0, NKROW)
  int k = (row >= NROW) ? 1 : 0;
  int bv = row - k * NROW;
  int b = bv / VV;
  const float4* enc4 = (const float4*)(encIn + (size_t)b * VV * DD);
  const int* cols = nb_cols + nb_base(row);
  int n = nb_cnt[row];
  int sub = lane >> 4, q = lane & 15;
  float ax = 0.0f, ay = 0.0f, az = 0.0f, aw = 0.0f;
  int j = 0;
  for (; j + 16 <= n; j += 16) {
    int c0 = cols[j + sub];
    int c1 = cols[j + 4 + sub];
    int c2 = cols[j + 8 + sub];
    int c3 = cols[j + 12 + sub];
    float4 v0 = enc4[(size_t)c0 * 16 + q];
    float4 v1 = enc4[(size_t)c1 * 16 + q];
    float4 v2 = enc4[(size_t)c2 * 16 + q];
    float4 v3 = enc4[(size_t)c3 * 16 + q];
    ax += (v0.x + v1.x) + (v2.x + v3.x);
    ay += (v0.y + v1.y) + (v2.y + v3.y);
    az += (v0.z + v1.z) + (v2.z + v3.z);
    aw += (v0.w + v1.w) + (v2.w + v3.w);
  }
  for (; j < n; j += 4) {
    int idx = j + sub;
    if (idx < n) {
      float4 v = enc4[(size_t)cols[idx] * 16 + q];
      ax += v.x; ay += v.y; az += v.z; aw += v.w;
    }
  }
#pragma unroll
  for (int o = 16; o < 64; o <<= 1) {
    ax += __shfl_xor(ax, o, 64);
    ay += __shfl_xor(ay, o, 64);
    az += __shfl_xor(az, o, 64);
    aw += __shfl_xor(aw, o, 64);
  }
  if (lane < 16) {
    float inv = 1.0f / fmaxf((float)n, 1.0f);
    float4 r; r.x = ax * inv; r.y = ay * inv; r.z = az * inv; r.w = aw * inv;
    ((float4*)(msg + (size_t)row * DD))[q] = r;
  }
}

// ---------------- agg GEMM + attention scores: 32 rows/block ----------------
__global__ void __launch_bounds__(256) k_aggatt(
    const float* __restrict__ msg,
    const float* __restrict__ agg_w, const float* __restrict__ agg_b,
    const float* __restrict__ att_w, const float* __restrict__ att_b,
    const float* __restrict__ att_v,
    float* __restrict__ agg, float* __restrict__ scores) {
  __shared__ float M[32][65];
  __shared__ float G[32][65];
  __shared__ float scp[NH][32][8];
  int tid = threadIdx.x;
  int tile0 = blockIdx.x * 32;            // [0, NKROW)
  int k = (tile0 >= NROW) ? 1 : 0;
  int bv0 = tile0 - k * NROW;
  for (int rep = 0; rep < 8; ++rep) {
    int idx = rep * 256 + tid; int i = idx >> 6, d = idx & 63;
    M[i][d] = msg[(size_t)(tile0 + i) * DD + d];
  }
  __syncthreads();
  int r = tid >> 3, cg = tid & 7;
  int c0 = cg * 8;
  const float* W = agg_w + (size_t)k * DD * DD;
  float a[8];
#pragma unroll
  for (int jj = 0; jj < 8; ++jj) a[jj] = agg_b[k * DD + c0 + jj];
#pragma unroll 4
  for (int kk = 0; kk < DD; ++kk) {
    float x = M[r][kk];
    const float4* wr4 = (const float4*)(W + kk * DD + c0);
    float4 u0 = wr4[0], u1 = wr4[1];
    a[0] = fmaf(x, u0.x, a[0]); a[1] = fmaf(x, u0.y, a[1]);
    a[2] = fmaf(x, u0.z, a[2]); a[3] = fmaf(x, u0.w, a[3]);
    a[4] = fmaf(x, u1.x, a[4]); a[5] = fmaf(x, u1.y, a[5]);
    a[6] = fmaf(x, u1.z, a[6]); a[7] = fmaf(x, u1.w, a[7]);
  }
#pragma unroll
  for (int jj = 0; jj < 8; ++jj) G[r][c0 + jj] = tanh_f(a[jj]);
  __syncthreads();
  for (int rep = 0; rep < 8; ++rep) {
    int idx = rep * 256 + tid; int i = idx >> 6, d = idx & 63;
    agg[(size_t)(tile0 + i) * DD + d] = G[i][d];
  }
#pragma unroll
  for (int h = 0; h < NH; ++h) {
    const float* Wh = att_w + (size_t)h * DD * DD;
    float a2[8];
#pragma unroll
    for (int jj = 0; jj < 8; ++jj) a2[jj] = att_b[h * DD + c0 + jj];
#pragma unroll 4
    for (int kk = 0; kk < DD; ++kk) {
      float x = G[r][kk];
      const float4* wr4 = (const float4*)(Wh + kk * DD + c0);
      float4 u0 = wr4[0], u1 = wr4[1];
      a2[0] = fmaf(x, u0.x, a2[0]); a2[1] = fmaf(x, u0.y, a2[1]);
      a2[2] = fmaf(x, u0.z, a2[2]); a2[3] = fmaf(x, u0.w, a2[3]);
      a2[4] = fmaf(x, u1.x, a2[4]); a2[5] = fmaf(x, u1.y, a2[5]);
      a2[6] = fmaf(x, u1.z, a2[6]); a2[7] = fmaf(x, u1.w, a2[7]);
    }
    float p = 0.0f;
#pragma unroll
    for (int jj = 0; jj < 8; ++jj) p += tanh_f(a2[jj]) * att_v[h * DD + c0 + jj];
    scp[h][r][cg] = p;
  }
  __syncthreads();
  if (tid < NH * 32) {
    int h = tid >> 5, i = tid & 31;
    float s = 0.0f;
#pragma unroll
    for (int c = 0; c < 8; ++c) s += scp[h][i][c];
    scores[(size_t)(h * KH + k) * NROW + bv0 + i] = s;
  }
}

// ---------------- attention mix + GRU (+ fused decode), 32 rows/block ----------------
__global__ void __launch_bounds__(256) k_gru(
    const float* __restrict__ encIn, const float* __restrict__ agg,
    const float* __restrict__ scores,
    const float* __restrict__ wu, const float* __restrict__ bu,
    const float* __restrict__ wr, const float* __restrict__ br,
    const float* __restrict__ wc, const float* __restrict__ bc,
    float* __restrict__ encOut,
    int do_decode,
    const float* __restrict__ dw0, const float* __restrict__ db0,
    const float* __restrict__ dw1, const float* __restrict__ db1,
    const float* __restrict__ uw0, const float* __restrict__ ub0,
    const float* __restrict__ uw1, const float* __restrict__ ub1,
    float* __restrict__ pred, float* __restrict__ dualp) {
  __shared__ float X[32][129];     // [row][0..63]=nxt, [64..127]=enc then r*enc
  __shared__ float R[32][65];      // eo tile for decode
  __shared__ float wmix[2][32];
  __shared__ float scred[2][32][8];
  int tid = threadIdx.x;
  int tile0 = blockIdx.x * 32;
  for (int rep = 0; rep < 8; ++rep) {
    int idx = rep * 256 + tid; int i = idx >> 6, d = idx & 63;
    X[i][64 + d] = encIn[(size_t)(tile0 + i) * DD + d];
  }
  if (tid < 32) {
    int i = tid;
    float W0 = 0.0f, W1 = 0.0f;
#pragma unroll
    for (int h = 0; h < NH; ++h) {
      float s0 = scores[(size_t)(h * KH + 0) * NROW + tile0 + i];
      float s1 = scores[(size_t)(h * KH + 1) * NROW + tile0 + i];
      float m = fmaxf(s0, s1);
      float e0 = __expf(s0 - m), e1 = __expf(s1 - m);
      float inv = 1.0f / (e0 + e1);
      W0 += e0 * inv; W1 += e1 * inv;
    }
    wmix[0][i] = W0 * 0.25f;
    wmix[1][i] = W1 * 0.25f;
  }
  __syncthreads();
  for (int rep = 0; rep < 8; ++rep) {
    int idx = rep * 256 + tid; int i = idx >> 6, d = idx & 63;
    float a0 = agg[(size_t)(tile0 + i) * DD + d];
    float a1 = agg[(size_t)(NROW + tile0 + i) * DD + d];
    X[i][d] = wmix[0][i] * a0 + wmix[1][i] * a1;
  }
  __syncthreads();
  int r = tid >> 3, cg = tid & 7;
  int c0 = cg * 8;
  // u, r gates over xs=[nxt|enc]
  float au[8], ar[8];
#pragma unroll
  for (int jj = 0; jj < 8; ++jj) { au[jj] = bu[c0 + jj]; ar[jj] = br[c0 + jj]; }
#pragma unroll 4
  for (int kk = 0; kk < 2 * DD; ++kk) {
    float x = X[r][kk];
    const float4* wu4 = (const float4*)(wu + kk * DD + c0);
    const float4* wr4 = (const float4*)(wr + kk * DD + c0);
    float4 u0 = wu4[0], u1 = wu4[1];
    float4 r0 = wr4[0], r1 = wr4[1];
    au[0] = fmaf(x, u0.x, au[0]); au[1] = fmaf(x, u0.y, au[1]);
    au[2] = fmaf(x, u0.z, au[2]); au[3] = fmaf(x, u0.w, au[3]);
    au[4] = fmaf(x, u1.x, au[4]); au[5] = fmaf(x, u1.y, au[5]);
    au[6] = fmaf(x, u1.z, au[6]); au[7] = fmaf(x, u1.w, au[7]);
    ar[0] = fmaf(x, r0.x, ar[0]); ar[1] = fmaf(x, r0.y, ar[1]);
    ar[2] = fmaf(x, r0.z, ar[2]); ar[3] = fmaf(x, r0.w, ar[3]);
    ar[4] = fmaf(x, r1.x, ar[4]); ar[5] = fmaf(x, r1.y, ar[5]);
    ar[6] = fmaf(x, r1.z, ar[6]); ar[7] = fmaf(x, r1.w, ar[7]);
  }
  float uu[8], encv[8], rr[8];
#pragma unroll
  for (int jj = 0; jj < 8; ++jj) {
    uu[jj] = sigmoid_f(au[jj]);
    rr[jj] = sigmoid_f(ar[jj]);
    encv[jj] = X[r][64 + c0 + jj];      // read before overwrite
  }
  __syncthreads();                       // all waves done reading X
#pragma unroll
  for (int jj = 0; jj < 8; ++jj) X[r][64 + c0 + jj] = encv[jj] * rr[jj];
  __syncthreads();
  // candidate
  float ac[8];
#pragma unroll
  for (int jj = 0; jj < 8; ++jj) ac[jj] = bc[c0 + jj];
#pragma unroll 4
  for (int kk = 0; kk < 2 * DD; ++kk) {
    float x = X[r][kk];
    const float4* wc4 = (const float4*)(wc + kk * DD + c0);
    float4 u0 = wc4[0], u1 = wc4[1];
    ac[0] = fmaf(x, u0.x, ac[0]); ac[1] = fmaf(x, u0.y, ac[1]);
    ac[2] = fmaf(x, u0.z, ac[2]); ac[3] = fmaf(x, u0.w, ac[3]);
    ac[4] = fmaf(x, u1.x, ac[4]); ac[5] = fmaf(x, u1.y, ac[5]);
    ac[6] = fmaf(x, u1.z, ac[6]); ac[7] = fmaf(x, u1.w, ac[7]);
  }
  float eo[8];
#pragma unroll
  for (int jj = 0; jj < 8; ++jj) {
    float cc = tanh_f(ac[jj]);
    eo[jj] = uu[jj] * encv[jj] + (1.0f - uu[jj]) * cc;
    encOut[(size_t)(tile0 + r) * DD + c0 + jj] = eo[jj];
  }
  if (do_decode) {
#pragma unroll
    for (int jj = 0; jj < 8; ++jj) R[r][c0 + jj] = eo[jj];
    __syncthreads();
    float hd[8], hq[8];
#pragma unroll
    for (int jj = 0; jj < 8; ++jj) { hd[jj] = db0[c0 + jj]; hq[jj] = ub0[c0 + jj]; }
#pragma unroll 4
    for (int kk = 0; kk < DD; ++kk) {
      float x = R[r][kk];
      const float4* d4 = (const float4*)(dw0 + kk * DD + c0);
      const float4* q4 = (const float4*)(uw0 + kk * DD + c0);
      float4 u0 = d4[0], u1 = d4[1];
      float4 v0 = q4[0], v1 = q4[1];
      hd[0] = fmaf(x, u0.x, hd[0]); hd[1] = fmaf(x, u0.y, hd[1]);
      hd[2] = fmaf(x, u0.z, hd[2]); hd[3] = fmaf(x, u0.w, hd[3]);
      hd[4] = fmaf(x, u1.x, hd[4]); hd[5] = fmaf(x, u1.y, hd[5]);
      hd[6] = fmaf(x, u1.z, hd[6]); hd[7] = fmaf(x, u1.w, hd[7]);
      hq[0] = fmaf(x, v0.x, hq[0]); hq[1] = fmaf(x, v0.y, hq[1]);
      hq[2] = fmaf(x, v0.z, hq[2]); hq[3] = fmaf(x, v0.w, hq[3]);
      hq[4] = fmaf(x, v1.x, hq[4]); hq[5] = fmaf(x, v1.y, hq[5]);
      hq[6] = fmaf(x, v1.z, hq[6]); hq[7] = fmaf(x, v1.w, hq[7]);
    }
    float p = 0.0f, q = 0.0f;
#pragma unroll
    for (int jj = 0; jj < 8; ++jj) { p += hd[jj] * dw1[c0 + jj]; q += hq[jj] * uw1[c0 + jj]; }
    scred[0][r][cg] = p; scred[1][r][cg] = q;
    __syncthreads();
    if (tid < 32) {
      float s = db1[0];
#pragma unroll
      for (int c = 0; c < 8; ++c) s += scred[0][tid][c];
      pred[tile0 + tid] = s;
    } else if (tid < 64) {
      int i = tid - 32;
      float s = ub1[0];
#pragma unroll
      for (int c = 0; c < 8; ++c) s += scred[1][i][c];
      dualp[tile0 + i] = s;
    }
  }
}

// ------- fused: sparsemax (fixed-point tau) + CSC scatter + dual edge cost -------
__global__ void __launch_bounds__(256) k_primal_dual(
    const int* __restrict__ nb_cols, const int* __restrict__ nb_cnt,
    const float* __restrict__ pred, const float* __restrict__ dualp,
    const float* __restrict__ dem,
    float* __restrict__ rowsum,
    int* __restrict__ col_cnt, int* __restrict__ col_rows, float* __restrict__ col_vals,
    float* __restrict__ out) {
  __shared__ float bacc[BB];
  if (threadIdx.x < BB) bacc[threadIdx.x] = 0.0f;
  __syncthreads();
  int w = threadIdx.x >> 6, lane = threadIdx.x & 63;
  int row = blockIdx.x * 4 + w;
  int b = row / VV;
  int n = nb_cnt[row];
  int c = (lane < n) ? nb_cols[(size_t)row * CAP + lane] : 0;
  const float* predB = pred + (size_t)b * VV;
  const float* dualB = dualp + (size_t)b * VV;
  float z = (lane < n) ? predB[c] : -1e30f;
  float tau = 0.0f;
  if (n > 0) {
    bool in = (lane < n);
    for (int it = 0; it < 64; ++it) {
      float s = wredsum(in ? z : 0.0f);
      int cnt = (int)__popcll(__ballot(in));
      tau = (s - 1.0f) / (float)cnt;
      bool nin = (z > tau);
      if (__ballot(nin) == __ballot(in)) break;
      in = nin;
    }
  }
  float pv = (lane < n) ? fmaxf(z - tau, 0.0f) : 0.0f;
  float s2 = wredsum(pv * pv);
  if (lane == 0) rowsum[row] = s2;
  if (pv > 0.0f) {
    int g = b * VV + c;
    int j = atomicAdd(&col_cnt[g], 1);
    if (j < CAP) {
      col_rows[(size_t)g * CAP + j] = row - b * VV;
      col_vals[(size_t)g * CAP + j] = pv;
    }
  }
  float du = dualp[row];
  float es = 0.0f;
  if (lane < n) {
    float dd = du - dualB[c];
    float f = 0.0f, acm = 0.0f;
#pragma unroll
    for (int t = 0; t < 8; ++t) {
      float look = f - 0.9f * acm;
      float grad = 2.0f * look - dd;
      acm = 0.9f * acm + 0.1f * grad;
      f = fmaxf(f - acm, 0.0f);
    }
    es = f * f - dd * f;
  }
  float contrib = -es;
  if (lane == 0) contrib += du * dem[row];
  float ws_ = wredsum(contrib);
  if (lane == 0) atomicAdd(&bacc[b], ws_);
  __syncthreads();
  if (threadIdx.x < BB) {
    float t = bacc[threadIdx.x];
    if (t != 0.0f) atomicAdd(&out[threadIdx.x], t);
  }
}

// ------- fused flow iterations (per-graph block) + flow cost -------
__global__ void __launch_bounds__(1024) k_flow(
    const int* __restrict__ col_cnt, const int* __restrict__ col_rows,
    const float* __restrict__ col_vals, const float* __restrict__ dem,
    const float* __restrict__ rowsum, float* __restrict__ out) {
  __shared__ float aS[VV];
  __shared__ float red[16];
  int b = blockIdx.x;
  int tid = threadIdx.x;
  const float* demB = dem + (size_t)b * VV;
  for (int v = tid; v < VV; v += 1024) aS[v] = fmaxf(-demB[v], 0.0f);
  __syncthreads();
  for (int t = 0; t < 7; ++t) {
    float nv0 = 0.0f, nv1 = 0.0f;
    {
      int v = tid;
      if (v < VV) {
        int g = b * VV + v;
        int n = col_cnt[g]; if (n > CAP) n = CAP;
        const int* cr = col_rows + (size_t)g * CAP;
        const float* cv = col_vals + (size_t)g * CAP;
        float acc = 0.0f;
        for (int j = 0; j < n; ++j) acc += cv[j] * aS[cr[j]];
        nv0 = fmaxf(acc - demB[v], 0.0f);
      }
      v = tid + 1024;
      if (v < VV) {
        int g = b * VV + v;
        int n = col_cnt[g]; if (n > CAP) n = CAP;
        const int* cr = col_rows + (size_t)g * CAP;
        const float* cv = col_vals + (size_t)g * CAP;
        float acc = 0.0f;
        for (int j = 0; j < n; ++j) acc += cv[j] * aS[cr[j]];
        nv1 = fmaxf(acc - demB[v], 0.0f);
      }
    }
    __syncthreads();
    if (tid < VV) aS[tid] = nv0;
    if (tid + 1024 < VV) aS[tid + 1024] = nv1;
    __syncthreads();
  }
  float fc = 0.0f;
  for (int v = tid; v < VV; v += 1024) { float a = aS[v]; fc += a * a * rowsum[b * VV + v]; }
  fc = wredsum(fc);
  int wid = tid >> 6, lane = tid & 63;
  if (lane == 0) red[wid] = fc;
  __syncthreads();
  if (tid == 0) {
    float s = 0.0f;
#pragma unroll
    for (int i = 0; i < 16; ++i) s += red[i];
    atomicAdd(&out[b], s);
  }
}

extern "C" void kernel_launch(void* const* d_in, const int* in_sizes, int n_in,
                              void* d_out, int out_size, void* d_ws, size_t ws_size,
                              hipStream_t stream) {
  const float* feat   = (const float*)d_in[0];
  const float* emb    = (const float*)d_in[1];
  const float* dem    = (const float*)d_in[2];
  const float* nb     = (const float*)d_in[4];   // [K,B,V,V]
  const float* enc_w0 = (const float*)d_in[5];
  const float* enc_b0 = (const float*)d_in[6];
  const float* enc_w1 = (const float*)d_in[7];
  const float* enc_b1 = (const float*)d_in[8];
  const float* agg_w  = (const float*)d_in[9];
  const float* agg_b  = (const float*)d_in[10];
  const float* att_w  = (const float*)d_in[11];
  const float* att_b  = (const float*)d_in[12];
  const float* att_v  = (const float*)d_in[13];
  const float* gru_wu = (const float*)d_in[14];
  const float* gru_bu = (const float*)d_in[15];
  const float* gru_wr = (const float*)d_in[16];
  const float* gru_br = (const float*)d_in[17];
  const float* gru_wc = (const float*)d_in[18];
  const float* gru_bc = (const float*)d_in[19];
  const float* dec_w0 = (const float*)d_in[20];
  const float* dec_b0 = (const float*)d_in[21];
  const float* dec_w1 = (const float*)d_in[22];
  const float* dec_b1 = (const float*)d_in[23];
  const float* dual_w0= (const float*)d_in[24];
  const float* dual_b0= (const float*)d_in[25];
  const float* dual_w1= (const float*)d_in[26];
  const float* dual_b1= (const float*)d_in[27];
  float* out = (float*)d_out;

  float* ws = (float*)d_ws;
  float* enc0     = ws;                              // NROW*DD
  float* enc1     = enc0 + (size_t)NROW * DD;
  float* msg      = enc1 + (size_t)NROW * DD;        // NKROW*DD
  float* aggbuf   = msg + (size_t)NKROW * DD;        // NKROW*DD
  float* scores   = aggbuf + (size_t)NKROW * DD;     // NH*KH*NROW
  float* pred     = scores + (size_t)NH * KH * NROW;
  float* dualp    = pred + NROW;
  float* rowsum   = dualp + NROW;
  float* col_vals = rowsum + NROW;                   // NROW*CAP
  int* col_cnt  = (int*)(col_vals + (size_t)NROW * CAP);
  int* nb_cnt   = col_cnt + NROW;                    // NKROW
  int* col_rows = nb_cnt + NKROW;                    // NROW*CAP
  int* nb_cols  = col_rows + (size_t)NROW * CAP;

  (void)in_sizes; (void)n_in; (void)ws_size;

  hipMemsetAsync(out, 0, (size_t)out_size * sizeof(float), stream);
  hipMemsetAsync(col_cnt, 0, (size_t)NROW * sizeof(int), stream);

  k_nbcsr<<<NKROW / 4, 256, 0, stream>>>(nb, nb_cols, nb_cnt);
  k_encoder<<<NROW / 32, 256, 0, stream>>>(emb, feat, enc_w0, enc_b0, enc_w1, enc_b1, enc0);

  const float* encIn = enc0;
  float* encOut = enc1;
  for (int l = 0; l < 2; ++l) {
    k_gather<<<NKROW / 4, 256, 0, stream>>>(nb_cols, nb_cnt, encIn, msg);
    k_aggatt<<<NKROW / 32, 256, 0, stream>>>(msg, agg_w, agg_b, att_w, att_b, att_v,
                                             aggbuf, scores);
    k_gru<<<NROW / 32, 256, 0, stream>>>(encIn, aggbuf, scores,
                                         gru_wu, gru_bu, gru_wr, gru_br, gru_wc, gru_bc,
                                         encOut,
                                         (l == 1) ? 1 : 0,
                                         dec_w0, dec_b0, dec_w1, dec_b1,
                                         dual_w0, dual_b0, dual_w1, dual_b1, pred, dualp);
    const float* t = encIn; encIn = encOut; encOut = (float*)t;
  }

  k_primal_dual<<<NROW / 4, 256, 0, stream>>>(nb_cols, nb_cnt, pred, dualp, dem,
                                              rowsum, col_cnt, col_rows, col_vals, out);
  k_flow<<<BB, 1024, 0, stream>>>(col_cnt, col_rows, col_vals, dem, rowsum, out);
}